// Round 18
// baseline (613.180 us; speedup 1.0000x reference)
//
#include <hip/hip_runtime.h>
#include <hip/hip_bf16.h>

typedef short short8 __attribute__((ext_vector_type(8)));
typedef short short4v __attribute__((ext_vector_type(4)));
typedef float f32x4 __attribute__((ext_vector_type(4)));
typedef __hip_bfloat16 bf16;

constexpr int NB   = 32;     // batch
constexpr int NL   = 720;    // seq len
constexpr int ND   = 862;    // channels
constexpr int NS   = 60;     // L/PERIOD
constexpr int NSER = NB * ND;    // 27584 series / GEMM rows
constexpr int NKP  = 736;    // 720 padded to 32
constexpr int NOUT = 1560;   // output rows per batch
constexpr int NMT  = 216;    // ceil(27584/128), divisible by 8 (XCD grouping)
constexpr int NMT64 = 432;   // ceil(27584/64) padded to mult of 8

__device__ __forceinline__ void gload16(const void* g, void* l) {
  __builtin_amdgcn_global_load_lds((const __attribute__((address_space(1))) void*)g,
                                   (__attribute__((address_space(3))) void*)l, 16, 0, 0);
}

// ---------------- fused init: twiddle table + weight casts + row sums ----------------

__device__ __forceinline__ void cvt_job(const float* __restrict__ src, bf16* __restrict__ dst,
                                        int rows, int cols, int rowsPad, int colsPad,
                                        int gid, int gsz) {
  int tot = rowsPad * colsPad;
  for (int i = gid; i < tot; i += gsz) {
    int r = i / colsPad, c = i - r * colsPad;
    float v = (r < rows && c < cols) ? src[r * cols + c] : 0.f;
    dst[i] = __float2bfloat16(v);
  }
}

__global__ __launch_bounds__(256) void k_init(
    const float* __restrict__ w_in_m, const float* __restrict__ w_raw_m,
    const float* __restrict__ w_in_s, const float* __restrict__ w_raw_s,
    const float* __restrict__ w_out_m, const float* __restrict__ w_out_s,
    const float* __restrict__ w_f1, const float* __restrict__ w_f2,
    double2* __restrict__ tw,
    bf16* __restrict__ Wb_in_m, bf16* __restrict__ Wb_raw_m,
    bf16* __restrict__ Wb_in_s, bf16* __restrict__ Wb_raw_s,
    bf16* __restrict__ Wb_out_m, bf16* __restrict__ Wb_out_s,
    bf16* __restrict__ Wb_f1, bf16* __restrict__ Wb_f2,
    float* __restrict__ S_in, float* __restrict__ S_raw) {
  int gid = blockIdx.x * 256 + threadIdx.x;
  int gsz = gridDim.x * 256;
  for (int j = gid; j < 720; j += gsz) {
    double a = (double)j / 360.0;          // W720^j = exp(-2*pi*i*j/720)
    tw[j] = make_double2(cospi(a), -sinpi(a));
  }
  cvt_job(w_in_m,  Wb_in_m,  512,  60, 512,   64, gid, gsz);
  cvt_job(w_raw_m, Wb_raw_m, 512, 720, 512,  NKP, gid, gsz);
  cvt_job(w_in_s,  Wb_in_s,  512,  60, 512,   64, gid, gsz);
  cvt_job(w_raw_s, Wb_raw_s, 512, 720, 512,  NKP, gid, gsz);
  cvt_job(w_out_m, Wb_out_m,  60, 1024, 64, 1024, gid, gsz);
  cvt_job(w_out_s, Wb_out_s,  60, 1024, 64, 1024, gid, gsz);
  cvt_job(w_f1,    Wb_f1,     64,  720, 64,  NKP, gid, gsz);
  cvt_job(w_f2,    Wb_f2,    720,   64, 768,  64, gid, gsz);
  for (int i = gid; i < 512; i += gsz) {
    float acc = 0.f;
    for (int j = 0; j < 60; j++) acc += w_in_m[(size_t)i * 60 + j];
    S_in[i] = acc;
  }
  for (int i = gid; i < 512; i += gsz) {
    float acc = 0.f;
    for (int j = 0; j < 720; j++) acc += w_raw_m[(size_t)i * 720 + j];
    S_raw[i] = acc;
  }
}

// ---------------- prep: stats + normalize + transposes ----------------
// 1D grid 5376 = 8 XCDs x 672; all 12 t-chunks of one (batch, d-tile) land on
// the SAME XCD consecutively -> its L2 merges partial-line writes.
__global__ __launch_bounds__(256, 8) void k_prep(const float* __restrict__ x, float* __restrict__ dout,
                                                 bf16* __restrict__ AT, bf16* __restrict__ MT,
                                                 bf16* __restrict__ ST, double* __restrict__ muPart) {
  __shared__ float xs[60][65];
  int gid = blockIdx.x;
  int xcd = gid & 7, r = gid >> 3;
  int tc = r % 12, q = r / 12;
  int db = q * 8 + xcd;            // 0..447 = (d-tile)*32 + b
  int d0 = (db >> 5) * 64, b = db & 31;
  int tid = threadIdx.x;
  int t0 = tc * 60;
  // phase 1: coalesced raw load, float2-vectorized (row offsets are even)
  for (int i = tid; i < 60 * 32; i += 256) {
    int t = i >> 5, dq = i & 31, d = d0 + dq * 2;
    float2 v;
    if (d + 1 < ND) {
      v = *(const float2*)(x + ((size_t)b * NL + t0 + t) * ND + d);
    } else {
      v.x = (d < ND) ? x[((size_t)b * NL + t0 + t) * ND + d] : 0.f;
      v.y = 0.f;
    }
    xs[t][dq * 2] = v.x;
    xs[t][dq * 2 + 1] = v.y;
  }
  __syncthreads();
  // phase 2a: AT = bf16(x^T) row chunk (raw values) + f64 partial sums for mu
  for (int i = tid; i < 64 * 15; i += 256) {
    int dl = i & 63, tq = i >> 6, d = d0 + dl;
    if (d < ND) {
      union { bf16 h[4]; short4v v; } u;
#pragma unroll
      for (int r2 = 0; r2 < 4; r2++) u.h[r2] = __float2bfloat16(xs[tq * 4 + r2][dl]);
      *(short4v*)(AT + (size_t)(b * ND + d) * NKP + t0 + tq * 4) = u.v;
    }
  }
  if (tid < 64) {
    int d = d0 + tid;
    if (d < ND) {
      double s = 0.0;
      for (int t = 0; t < 60; t++) s += (double)xs[t][tid];
      muPart[(size_t)(b * ND + d) * 12 + tc] = s;
    }
  }
  if (tc == 11) {  // zero pads once per (b,d)
    for (int i = tid; i < 64 * 16; i += 256) {
      int dl = i >> 4, c = 720 + (i & 15), d = d0 + dl;
      if (d < ND) AT[(size_t)(b * ND + d) * NKP + c] = __float2bfloat16(0.f);
    }
    if (tid < 64 * 4) {
      int dl = tid >> 2, s = 60 + (tid & 3), d = d0 + dl;
      if (d < ND) {
        MT[(size_t)(b * ND + d) * 64 + s] = __float2bfloat16(0.f);
        ST[(size_t)(b * ND + d) * 64 + s] = __float2bfloat16(0.f);
      }
    }
  }
  __syncthreads();
  // phase 2b: per-period stats, numpy-bit-exact f32 (sequential sums, no FMA)
  for (int i = tid; i < 64 * 5; i += 256) {
    int dl = i & 63, sp = i >> 6, d = d0 + dl;
    float v[12];
#pragma unroll
    for (int j = 0; j < 12; j++) v[j] = xs[sp * 12 + j][dl];
    float sum = 0.f;
#pragma unroll
    for (int j = 0; j < 12; j++) sum = __fadd_rn(sum, v[j]);
    float m = __fdiv_rn(sum, 12.f);
    float ss = 0.f;
#pragma unroll
    for (int j = 0; j < 12; j++) { float dj = __fsub_rn(v[j], m); ss = __fadd_rn(ss, __fmul_rn(dj, dj)); }
    float sd = __fsqrt_rn(__fdiv_rn(ss, 11.f));
    float den = __fadd_rn(sd, 1e-8f);
#pragma unroll
    for (int j = 0; j < 12; j++) xs[sp * 12 + j][dl] = __fdiv_rn(__fsub_rn(v[j], m), den);
    if (d < ND) {
      MT[(size_t)(b * ND + d) * 64 + tc * 5 + sp] = __float2bfloat16(m);
      ST[(size_t)(b * ND + d) * 64 + tc * 5 + sp] = __float2bfloat16(sd);
    }
  }
  __syncthreads();
  // phase 3: norm^T chunk into d_out's pred_main region (scratch until MODE6)
  float* nt = dout + ((size_t)b * NOUT + 720) * ND;
  for (int i = tid; i < 64 * 15; i += 256) {
    int dl = i & 63, tq = i >> 6, d = d0 + dl;
    if (d < ND) {
      float4 f;
      f.x = xs[tq * 4 + 0][dl]; f.y = xs[tq * 4 + 1][dl];
      f.z = xs[tq * 4 + 2][dl]; f.w = xs[tq * 4 + 3][dl];
      *(float4*)(nt + (size_t)d * 720 + t0 + tq * 4) = f;
    }
  }
}

__global__ __launch_bounds__(256) void k_mured(const double* __restrict__ muPart, float* __restrict__ mu) {
  int ser = blockIdx.x * 256 + threadIdx.x;
  if (ser < NSER) {
    const double* p = muPart + (size_t)ser * 12;
    double s = 0.0;
#pragma unroll
    for (int j = 0; j < 12; j++) s += p[j];
    mu[ser] = (float)(s / 720.0);
  }
}

// ---------------- fp64 FFT (720 = 16*9*5), 2 packed pairs (4 series) per block ----------------
// 256 threads = 2 halves of 128; each half runs one packed FFT in its own LDS
// buffer. Tests/exploits the per-CU workgroup-count cap: same resident blocks,
// 2x waves. Block-wide barriers are safe (both halves run identical phases).
#define PIDX(i) ((i) + ((i) >> 4))

__device__ __forceinline__ void dft3(double x0r, double x0i, double x1r, double x1i,
                                     double x2r, double x2i, double s3,
                                     double& y0r, double& y0i, double& y1r, double& y1i,
                                     double& y2r, double& y2i) {
  double ur = x1r + x2r, ui = x1i + x2i;
  double wr = x1r - x2r, wi = x1i - x2i;
  double mr = x0r - 0.5 * ur, mi = x0i - 0.5 * ui;
  y0r = x0r + ur;      y0i = x0i + ui;
  y1r = mr + s3 * wi;  y1i = mi - s3 * wr;
  y2r = mr - s3 * wi;  y2i = mi + s3 * wr;
}

__device__ __forceinline__ void dft4(double x0r, double x0i, double x1r, double x1i,
                                     double x2r, double x2i, double x3r, double x3i,
                                     double& y0r, double& y0i, double& y1r, double& y1i,
                                     double& y2r, double& y2i, double& y3r, double& y3i) {
  double a0r = x0r + x2r, a0i = x0i + x2i;
  double a1r = x0r - x2r, a1i = x0i - x2i;
  double a2r = x1r + x3r, a2i = x1i + x3i;
  double a3r = x1r - x3r, a3i = x1i - x3i;
  y0r = a0r + a2r; y0i = a0i + a2i;
  y2r = a0r - a2r; y2i = a0i - a2i;
  y1r = a1r + a3i; y1i = a1i - a3r;   // + (-i)*a3
  y3r = a1r - a3i; y3i = a1i + a3r;   // + (+i)*a3
}

__device__ __forceinline__ void cmulw(double& xr, double& xi, double2 w) {
  double r = xr * w.x - xi * w.y;
  double i = xr * w.y + xi * w.x;
  xr = r; xi = i;
}

__global__ __launch_bounds__(256) void k_fft(const float* __restrict__ dout, const double2* __restrict__ twg,
                                             unsigned short* __restrict__ selK, float* __restrict__ selA,
                                             float* __restrict__ selB, int* __restrict__ selCnt,
                                             int blkoff) {
  __shared__ double reb[2][765], imb[2][765];
  int tid = threadIdx.x;
  int half = tid >> 7, t2 = tid & 127;
  int pair = 2 * (blockIdx.x + blkoff) + half;   // pairs never cross a batch (862 even)
  int ser0 = 2 * pair;
  int b = ser0 / ND, d0 = ser0 - b * ND;
  double* re = reb[half];
  double* im = imb[half];
  double s3 = -twg[240].y;                                 // sin(2*pi/3)
  double2 w9_1 = twg[80], w9_2 = twg[160], w9_4 = twg[320];
  double2 w16_1 = twg[45], w16_2 = twg[90], w16_3 = twg[135];
  double2 w16_4 = twg[180], w16_6 = twg[270], w16_9 = twg[405];
  double w5r[5], w5i[5];
#pragma unroll
  for (int j = 0; j < 5; j++) { double2 t = twg[144 * j]; w5r[j] = t.x; w5i[j] = t.y; }

  const float* row0 = dout + ((size_t)b * NOUT + 720) * ND + (size_t)d0 * 720;
  for (int n = t2; n < 720; n += 128) {
    re[PIDX(n)] = (double)row0[n];
    im[PIDX(n)] = (double)row0[720 + n];
  }
  __syncthreads();
  // step 1: 144 DFT-5 (stride 144)
  for (int task = t2; task < 144; task += 128) {
    double ar[5], ai[5], orr[5], oi[5];
#pragma unroll
    for (int n3 = 0; n3 < 5; n3++) { int p = PIDX(task + 144 * n3); ar[n3] = re[p]; ai[n3] = im[p]; }
    orr[0] = ar[0] + ar[1] + ar[2] + ar[3] + ar[4];
    oi[0]  = ai[0] + ai[1] + ai[2] + ai[3] + ai[4];
#pragma unroll
    for (int k3 = 1; k3 < 5; k3++) {
      double sr = ar[0], si = ai[0];
#pragma unroll
      for (int n3 = 1; n3 < 5; n3++) {
        int j = (n3 * k3) % 5;
        sr += ar[n3] * w5r[j] - ai[n3] * w5i[j];
        si += ar[n3] * w5i[j] + ai[n3] * w5r[j];
      }
      orr[k3] = sr; oi[k3] = si;
    }
#pragma unroll
    for (int k3 = 0; k3 < 5; k3++) { int p = PIDX(task + 144 * k3); re[p] = orr[k3]; im[p] = oi[k3]; }
  }
  __syncthreads();
  // step 2: 80 DFT-9 (stride 16) with pre-twiddle; 9 = 3x3 butterfly
  if (t2 < 80) {
    int task = t2;
    int n1 = task & 15, k3 = task >> 4;
    double xr[9], xi[9];
#pragma unroll
    for (int n2 = 0; n2 < 9; n2++) {
      int p = PIDX(n1 + 16 * n2 + 144 * k3);
      double a = re[p], bb = im[p];
      double2 w = twg[16 * n2 * k3];        // < 720 always
      xr[n2] = a * w.x - bb * w.y;
      xi[n2] = a * w.y + bb * w.x;
    }
    double tr[3][3], ti[3][3];
#pragma unroll
    for (int a = 0; a < 3; a++)
      dft3(xr[a], xi[a], xr[a + 3], xi[a + 3], xr[a + 6], xi[a + 6], s3,
           tr[a][0], ti[a][0], tr[a][1], ti[a][1], tr[a][2], ti[a][2]);
    cmulw(tr[1][1], ti[1][1], w9_1);
    cmulw(tr[1][2], ti[1][2], w9_2);
    cmulw(tr[2][1], ti[2][1], w9_2);
    cmulw(tr[2][2], ti[2][2], w9_4);
#pragma unroll
    for (int c = 0; c < 3; c++) {
      double y0r, y0i, y1r, y1i, y2r, y2i;
      dft3(tr[0][c], ti[0][c], tr[1][c], ti[1][c], tr[2][c], ti[2][c], s3,
           y0r, y0i, y1r, y1i, y2r, y2i);
      int p0 = PIDX(n1 + 16 * (c + 0) + 144 * k3);
      int p1 = PIDX(n1 + 16 * (c + 3) + 144 * k3);
      int p2 = PIDX(n1 + 16 * (c + 6) + 144 * k3);
      re[p0] = y0r; im[p0] = y0i;
      re[p1] = y1r; im[p1] = y1i;
      re[p2] = y2r; im[p2] = y2i;
    }
  }
  __syncthreads();
  // step 3: 45 DFT-16 with pre-twiddle; 16 = 4x4 butterfly; write Z linear
  double vr[16], vi[16];
  int k2 = 0, k3 = 0;
  bool act = t2 < 45;
  if (act) {
    k2 = t2 % 9; k3 = t2 / 9;
    int base = 16 * k2 + 144 * k3, tf = k3 + 5 * k2;
    int idx = 0;
#pragma unroll
    for (int n1 = 0; n1 < 16; n1++) {
      int p = PIDX(base + n1);
      double a = re[p], bb = im[p];
      double2 w = twg[idx];                 // idx = n1*tf <= 660
      vr[n1] = a * w.x - bb * w.y;
      vi[n1] = a * w.y + bb * w.x;
      idx += tf;
    }
  }
  __syncthreads();  // all reads done before overwriting with Z
  if (act) {
    int kbase = k3 + 5 * k2;
    double t1r[4][4], t1i[4][4];
#pragma unroll
    for (int a = 0; a < 4; a++)
      dft4(vr[a], vi[a], vr[a + 4], vi[a + 4], vr[a + 8], vi[a + 8], vr[a + 12], vi[a + 12],
           t1r[a][0], t1i[a][0], t1r[a][1], t1i[a][1],
           t1r[a][2], t1i[a][2], t1r[a][3], t1i[a][3]);
    cmulw(t1r[1][1], t1i[1][1], w16_1);
    cmulw(t1r[1][2], t1i[1][2], w16_2);
    cmulw(t1r[1][3], t1i[1][3], w16_3);
    cmulw(t1r[2][1], t1i[2][1], w16_2);
    cmulw(t1r[2][2], t1i[2][2], w16_4);
    cmulw(t1r[2][3], t1i[2][3], w16_6);
    cmulw(t1r[3][1], t1i[3][1], w16_3);
    cmulw(t1r[3][2], t1i[3][2], w16_6);
    cmulw(t1r[3][3], t1i[3][3], w16_9);
#pragma unroll
    for (int c = 0; c < 4; c++) {
      double y0r, y0i, y1r, y1i, y2r, y2i, y3r, y3i;
      dft4(t1r[0][c], t1i[0][c], t1r[1][c], t1i[1][c],
           t1r[2][c], t1i[2][c], t1r[3][c], t1i[3][c],
           y0r, y0i, y1r, y1i, y2r, y2i, y3r, y3i);
      re[kbase + 45 * (c + 0)]  = y0r; im[kbase + 45 * (c + 0)]  = y0i;
      re[kbase + 45 * (c + 4)]  = y1r; im[kbase + 45 * (c + 4)]  = y1i;
      re[kbase + 45 * (c + 8)]  = y2r; im[kbase + 45 * (c + 8)]  = y2i;
      re[kbase + 45 * (c + 12)] = y3r; im[kbase + 45 * (c + 12)] = y3i;
    }
  }
  __syncthreads();
  // 4 waves: wave (half,wv) -> series ser0(half) + wv; concurrent selection.
  int lane = tid & 63, wv = (tid >> 6) & 1;
  unsigned long long key[6];
#pragma unroll
  for (int j = 0; j < 6; j++) {
    int k = lane + 64 * j;
    if (k <= 360) {
      int mk = (k == 0) ? 0 : 720 - k;
      double zr = re[k], zi = im[k], wr = re[mk], wi = im[mk];
      double m2;
      if (wv == 0) {
        double ra = 0.5 * (zr + wr), ia = 0.5 * (zi - wi);
        m2 = ra * ra + ia * ia;
      } else {
        double rb = 0.5 * (zi + wi), ib = 0.5 * (wr - zr);
        m2 = rb * rb + ib * ib;
      }
      key[j] = (__double_as_longlong(m2) & ~0x1FFull) | (unsigned long long)(511 - k);
    } else {
      key[j] = 0ull;
    }
  }
#define CSWP(a, b) { unsigned long long ka = key[a], kb = key[b]; \
                     key[a] = ka > kb ? ka : kb; key[b] = ka > kb ? kb : ka; }
  CSWP(0,1) CSWP(1,2) CSWP(2,3) CSWP(3,4) CSWP(4,5)
  CSWP(0,1) CSWP(1,2) CSWP(2,3) CSWP(3,4)
  CSWP(0,1) CSWP(1,2) CSWP(2,3)
  CSWP(0,1) CSWP(1,2)
  CSWP(0,1)
#undef CSWP
  {
    int ser = ser0 + wv;
    bool isB = (wv == 1);
    int used = 0, cnt = 0;
    while (used < 30) {
      unsigned long long m = key[0];
#pragma unroll
      for (int off = 32; off; off >>= 1) {
        unsigned long long o = __shfl_xor(m, off);
        m = (o > m) ? o : m;
      }
      int bk = 511 - (int)(m & 0x1FF);
      int w = (bk == 0 || bk == 360) ? 1 : 2;
      int take = (30 - used < w) ? (30 - used) : w;
      bool own = (key[0] == m);     // keys globally unique -> exactly one owner
      if (own) {
        int mk = (bk == 0) ? 0 : 720 - bk;
        double zr = re[bk], zi = im[bk], wr = re[mk], wi = im[mk];
        double cr, ci;
        if (!isB) { cr = 0.5 * (zr + wr); ci = 0.5 * (zi - wi); }
        else      { cr = 0.5 * (zi + wi); ci = 0.5 * (wr - zr); }
        double scale = (double)take / 720.0;
        selK[(size_t)ser * 32 + cnt] = (unsigned short)bk;
        selA[(size_t)ser * 32 + cnt] = (float)(scale * cr);
        selB[(size_t)ser * 32 + cnt] = (float)(scale * ci);
      }
      key[0] = own ? key[1] : key[0];
      key[1] = own ? key[2] : key[1];
      key[2] = own ? key[3] : key[2];
      key[3] = own ? key[4] : key[3];
      key[4] = own ? key[5] : key[4];
      key[5] = own ? 0ull   : key[5];
      used += take; cnt++;
    }
    if (lane == 0) selCnt[ser] = cnt;
  }
}

// ---------------- reconstruction: x_f, residual, bf16 A_f ----------------
// grid (14, 3, 32): 64 channels x 240 t per block; 12-wide t-tiles per wave.
__global__ __launch_bounds__(256, 6) void k_recon(float* __restrict__ dout, const unsigned short* __restrict__ selK,
                                                  const float* __restrict__ selA, const float* __restrict__ selB,
                                                  const int* __restrict__ selCnt, const double2* __restrict__ twg,
                                                  bf16* __restrict__ Af) {
  __shared__ unsigned short kk[64][31];
  __shared__ float AAc[64][31], BBc[64][31];
  __shared__ int cc[64];
  __shared__ float2 tbl[720];
  int b = blockIdx.z, tch = blockIdx.y, d0 = blockIdx.x * 64, tid = threadIdx.x;
  for (int j = tid; j < 720; j += 256) { double2 w = twg[j]; tbl[j] = make_float2((float)w.x, (float)w.y); }
  for (int i = tid; i < 64 * 30; i += 256) {
    int dl = i / 30, j = i - dl * 30, d = d0 + dl;
    if (d < ND) {
      size_t o = (size_t)(b * ND + d) * 32 + j;
      kk[dl][j] = selK[o]; AAc[dl][j] = selA[o]; BBc[dl][j] = selB[o];
    }
  }
  if (tid < 64) cc[tid] = (d0 + tid < ND) ? selCnt[b * ND + d0 + tid] : 0;
  if (tch == 0) {  // zero-pad Af cols 720..735 once
    for (int i = tid; i < 64 * 16; i += 256) {
      int r = i >> 4, c = 720 + (i & 15), dd = d0 + r;
      if (dd < ND) Af[(size_t)(b * ND + dd) * NKP + c] = __float2bfloat16(0.f);
    }
  }
  __syncthreads();
  int dl = tid & 63, tb = tid >> 6;
  int d = d0 + dl;
  bool valid = d < ND;
  const float* nrow = dout + ((size_t)b * NOUT + 720) * ND + (size_t)(valid ? d : 0) * 720;
  bf16* afrow = Af + (size_t)(b * ND + (valid ? d : 0)) * NKP;
  int n = cc[dl];
#pragma unroll
  for (int m = 0; m < 5; m++) {
    int t0 = tch * 240 + tb * 12 + m * 48;
    float a[12];
#pragma unroll
    for (int r = 0; r < 12; r++) a[r] = 0.f;
    for (int j = 0; j < n; j++) {
      int k = kk[dl][j];
      float Aj = AAc[dl][j], Bj = BBc[dl][j];
      float2 w = tbl[k];                       // e^{-i*2pi*k/720}
      float2 c = tbl[(k * t0) % 720];          // e^{-i*2pi*k*t0/720}
#pragma unroll
      for (int r = 0; r < 12; r++) {
        a[r] = fmaf(Aj, c.x, fmaf(Bj, c.y, a[r]));
        if (r < 11) {
          float nx = c.x * w.x - c.y * w.y;
          float ny = c.x * w.y + c.y * w.x;
          c.x = nx; c.y = ny;
        }
      }
    }
    if (valid) {
      union { bf16 h[12]; short4v v[3]; } u;
#pragma unroll
      for (int r = 0; r < 12; r++) u.h[r] = __float2bfloat16(a[r]);
      *(short4v*)(afrow + t0 + 0) = u.v[0];
      *(short4v*)(afrow + t0 + 4) = u.v[1];
      *(short4v*)(afrow + t0 + 8) = u.v[2];
      float4 n0 = *(const float4*)(nrow + t0 + 0);
      float4 n1 = *(const float4*)(nrow + t0 + 4);
      float4 n2 = *(const float4*)(nrow + t0 + 8);
      const float nv[12] = {n0.x, n0.y, n0.z, n0.w, n1.x, n1.y, n1.z, n1.w,
                            n2.x, n2.y, n2.z, n2.w};
#pragma unroll
      for (int r = 0; r < 12; r++)
        dout[((size_t)b * NOUT + (t0 + r)) * ND + d] = nv[r] - a[r];
    }
  }
}

// ---------------- MFMA GEMM, C = A(Mrows x K) * W(N x K)^T ----------------
// 2-phase double-buffered K-loop; BM/WAVES template picks tiling.
template <int BM, int BN, int MODE, bool XCD, int WAVES>
__global__ __launch_bounds__(WAVES * 64) void k_gemm(const bf16* __restrict__ A, int lda,
                                              const bf16* __restrict__ W, int ldb, int Ktiles,
                                              const float* __restrict__ bias, const float* __restrict__ rowMu,
                                              const float* __restrict__ colS, bf16* __restrict__ Hout, int hldc,
                                              int hoff, float* __restrict__ dout, const float* __restrict__ wgt,
                                              const float* __restrict__ meanall, int Mtiles, int Mrows) {
  __shared__ bf16 sA[2 * BM * 32];
  __shared__ bf16 sB[2 * BN * 32];
  const int M = Mrows;
  int Ntiles = gridDim.x / Mtiles;
  int bid = blockIdx.x;
  int mt, nt;
  if constexpr (XCD) {  // same-A blocks 8 apart (same XCD), consecutive in dispatch
    int xg = bid & 7, q = bid >> 3;
    nt = q % Ntiles;
    mt = (q / Ntiles) * 8 + xg;
  } else {
    mt = bid % Mtiles; nt = bid / Mtiles;
  }
  int tid = threadIdx.x, wave = tid >> 6, lane = tid & 63;
  constexpr int RN = BN / 32;
  constexpr int MI = (2 * BM) / (16 * WAVES);
  static_assert(MI >= 1, "bad tiling");
  int wr = (wave >> 1) * (16 * MI);
  int wc = (wave & 1) * (BN / 2);
  f32x4 zero = {0.f, 0.f, 0.f, 0.f};
  f32x4 acc[MI][RN];
#pragma unroll
  for (int i = 0; i < MI; i++)
#pragma unroll
    for (int j = 0; j < RN; j++) acc[i][j] = zero;
  int rl = lane >> 2;             // row within 16-row group
  int cb = (lane & 3) * 8;        // k-element offset of this lane's 16B

  constexpr int ACH = BM / 16, BCH = BN / 16;
  auto stage = [&](int buf, int kt) {
    for (int c = wave; c < ACH + BCH; c += WAVES) {
      if (c < ACH) {
        int grow = mt * BM + c * 16 + rl;
        if (grow > M - 1) grow = M - 1;
        gload16(A + (size_t)grow * lda + kt * 32 + cb,
                (char*)sA + (size_t)buf * (BM * 64) + (size_t)(c * 16) * 64);
      } else {
        int i = c - ACH;
        int gn = nt * BN + i * 16 + rl;
        gload16(W + (size_t)gn * ldb + kt * 32 + cb,
                (char*)sB + (size_t)buf * (BN * 64) + (size_t)(i * 16) * 64);
      }
    }
  };

  stage(0, 0);
  __syncthreads();
  for (int kt = 0; kt < Ktiles; kt++) {
    int cur = kt & 1;
    if (kt + 1 < Ktiles) stage(cur ^ 1, kt + 1);   // prefetch next tile
    int r16 = lane & 15, kb = (lane >> 4) * 16;
    const char* baseA = (const char*)sA + (size_t)cur * (BM * 64);
    const char* baseB = (const char*)sB + (size_t)cur * (BN * 64);
    short8 av[MI], bv[RN];
#pragma unroll
    for (int mi = 0; mi < MI; mi++)
      av[mi] = *(const short8*)(baseA + (size_t)(wr + mi * 16 + r16) * 64 + kb);
#pragma unroll
    for (int ni = 0; ni < RN; ni++)
      bv[ni] = *(const short8*)(baseB + (size_t)(wc + ni * 16 + r16) * 64 + kb);
#pragma unroll
    for (int mi = 0; mi < MI; mi++)
#pragma unroll
      for (int ni = 0; ni < RN; ni++)
        acc[mi][ni] = __builtin_amdgcn_mfma_f32_16x16x32_bf16(av[mi], bv[ni], acc[mi][ni], 0, 0, 0);
    __syncthreads();   // drains prefetch + guards buffer reuse
  }
  int cr = (lane >> 4) * 4, ccol = lane & 15;
#pragma unroll
  for (int mi = 0; mi < MI; mi++) {
#pragma unroll
    for (int ni = 0; ni < RN; ni++) {
      int gm0 = mt * BM + wr + mi * 16 + cr;
      int gn = nt * BN + wc + ni * 16 + ccol;
      f32x4 c = acc[mi][ni];
      if constexpr (MODE == 0 || MODE == 1) {
        float bb = bias[gn];
        float cs = (MODE == 0) ? colS[gn] : 0.f;
#pragma unroll
        for (int r = 0; r < 4; r++) {
          int gm = gm0 + r;
          if (gm < M) {
            float v = c[r] + bb;
            if constexpr (MODE == 0) v = tanhf(v - rowMu[gm] * cs);
            else v = fmaxf(v, 0.f);
            Hout[(size_t)gm * hldc + hoff + gn] = __float2bfloat16(v);
          }
        }
      } else if constexpr (MODE == 2 || MODE == 3) {
        if (gn < 60) {
          float bb = bias[gn];
#pragma unroll
          for (int r = 0; r < 4; r++) {
            int gm = gm0 + r;
            if (gm < M) {
              int bI = gm / ND, dd = gm - bI * ND;
              float v;
              if constexpr (MODE == 2) v = (c[r] + bb) * wgt[dd] + meanall[gm] * wgt[ND + dd];
              else v = fmaxf(c[r] + bb, 0.f);
              constexpr int rowoff = (MODE == 2) ? 1440 : 1500;
              dout[((size_t)bI * NOUT + rowoff + gn) * ND + dd] = v;
            }
          }
        }
      } else {  // MODE 6: rows = f2 output index p, cols = series (coalesced)
        int bI = gn / ND, dd = gn - bI * ND;
#pragma unroll
        for (int r = 0; r < 4; r++) {
          int pp = gm0 + r;
          if (pp < 720) {
            dout[((size_t)bI * NOUT + 720 + pp) * ND + dd] = c[r] + bias[pp];
          }
        }
      }
    }
  }
}

// ---------------- launcher ----------------

extern "C" void kernel_launch(void* const* d_in, const int* in_sizes, int n_in,
                              void* d_out, int out_size, void* d_ws, size_t ws_size,
                              hipStream_t stream) {
  (void)in_sizes; (void)n_in; (void)out_size; (void)ws_size;
  const float* x       = (const float*)d_in[0];
  const float* w_in_m  = (const float*)d_in[1];
  const float* b_in_m  = (const float*)d_in[2];
  const float* w_raw_m = (const float*)d_in[3];
  const float* b_raw_m = (const float*)d_in[4];
  const float* w_out_m = (const float*)d_in[5];
  const float* b_out_m = (const float*)d_in[6];
  const float* w_in_s  = (const float*)d_in[7];
  const float* b_in_s  = (const float*)d_in[8];
  const float* w_raw_s = (const float*)d_in[9];
  const float* b_raw_s = (const float*)d_in[10];
  const float* w_out_s = (const float*)d_in[11];
  const float* b_out_s = (const float*)d_in[12];
  const float* w_f1    = (const float*)d_in[13];
  const float* b_f1    = (const float*)d_in[14];
  const float* w_f2    = (const float*)d_in[15];
  const float* b_f2    = (const float*)d_in[16];
  const float* wgt     = (const float*)d_in[17];
  float* out = (float*)d_out;

  char* p = (char*)d_ws;
  size_t off = 0;
  auto carve = [&](size_t bytes) { char* r = p + off; off += (bytes + 255) & ~(size_t)255; return r; };

  bf16* AT      = (bf16*)carve((size_t)NSER * NKP * 2);
  bf16* Af      = (bf16*)carve((size_t)NSER * NKP * 2);
  bf16* MT      = (bf16*)carve((size_t)NSER * 64 * 2);
  bf16* ST      = (bf16*)carve((size_t)NSER * 64 * 2);
  bf16* Hf      = (bf16*)carve((size_t)NSER * 64 * 2);
  float* mu     = (float*)carve((size_t)NSER * 4);
  double* muPart = (double*)carve((size_t)NSER * 12 * 8);
  double2* tw   = (double2*)carve(720 * sizeof(double2));
  bf16* Wb_in_m  = (bf16*)carve((size_t)512 * 64 * 2);
  bf16* Wb_raw_m = (bf16*)carve((size_t)512 * NKP * 2);
  bf16* Wb_in_s  = (bf16*)carve((size_t)512 * 64 * 2);
  bf16* Wb_raw_s = (bf16*)carve((size_t)512 * NKP * 2);
  bf16* Wb_out_m = (bf16*)carve((size_t)64 * 1024 * 2);
  bf16* Wb_out_s = (bf16*)carve((size_t)64 * 1024 * 2);
  bf16* Wb_f1    = (bf16*)carve((size_t)64 * NKP * 2);
  bf16* Wb_f2    = (bf16*)carve((size_t)768 * 64 * 2);
  float* S_in    = (float*)carve(512 * 4);
  float* S_raw   = (float*)carve(512 * 4);
  // sel arrays are dead before H is first written -> overlay H on them
  char* selBase = p + off;
  unsigned short* selK = (unsigned short*)carve((size_t)NSER * 32 * 2);
  float* selA   = (float*)carve((size_t)NSER * 32 * 4);
  float* selB   = (float*)carve((size_t)NSER * 32 * 4);
  int* selCnt   = (int*)carve((size_t)NSER * 4);
  bf16* H = (bf16*)selBase;  // 27584 x 1024 bf16 (56.5 MB), reuses sel region

  k_init<<<512, 256, 0, stream>>>(w_in_m, w_raw_m, w_in_s, w_raw_s, w_out_m, w_out_s, w_f1, w_f2,
                                  tw, Wb_in_m, Wb_raw_m, Wb_in_s, Wb_raw_s, Wb_out_m, Wb_out_s,
                                  Wb_f1, Wb_f2, S_in, S_raw);

  k_prep<<<14 * 12 * 32, 256, 0, stream>>>(x, out, AT, MT, ST, muPart);
  k_mured<<<(NSER + 255) / 256, 256, 0, stream>>>(muPart, mu);
  // 2 pairs per 256-thread block; 6896 blocks total split into 2 dispatches
  k_fft<<<NSER / 8, 256, 0, stream>>>(out, tw, selK, selA, selB, selCnt, 0);
  k_fft<<<NSER / 8, 256, 0, stream>>>(out, tw, selK, selA, selB, selCnt, NSER / 8);
  k_recon<<<dim3(14, 3, 32), 256, 0, stream>>>(out, selK, selA, selB, selCnt, tw, Af);

  // mean MLP
  k_gemm<128, 128, 0, true, 8><<<NMT * 4, 512, 0, stream>>>(MT, 64, Wb_in_m, 64, 2, b_in_m, mu, S_in, H, 1024, 0,
                                                            nullptr, nullptr, nullptr, NMT, NSER);
  k_gemm<128, 128, 0, true, 8><<<NMT * 4, 512, 0, stream>>>(AT, NKP, Wb_raw_m, NKP, 23, b_raw_m, mu, S_raw, H, 1024, 512,
                                                            nullptr, nullptr, nullptr, NMT, NSER);
  k_gemm<64, 64, 2, true, 8><<<NMT64, 512, 0, stream>>>(H, 1024, Wb_out_m, 1024, 32, b_out_m, nullptr, nullptr,
                                                        nullptr, 0, 0, out, wgt, mu, NMT64, NSER);
  // std MLP (reuses H)
  k_gemm<128, 128, 1, true, 8><<<NMT * 4, 512, 0, stream>>>(ST, 64, Wb_in_s, 64, 2, b_in_s, nullptr, nullptr, H, 1024, 0,
                                                            nullptr, nullptr, nullptr, NMT, NSER);
  k_gemm<128, 128, 1, true, 8><<<NMT * 4, 512, 0, stream>>>(AT, NKP, Wb_raw_s, NKP, 23, b_raw_s, nullptr, nullptr, H, 1024, 512,
                                                            nullptr, nullptr, nullptr, NMT, NSER);
  k_gemm<64, 64, 3, true, 8><<<NMT64, 512, 0, stream>>>(H, 1024, Wb_out_s, 1024, 32, b_out_s, nullptr, nullptr,
                                                        nullptr, 0, 0, out, nullptr, nullptr, NMT64, NSER);
  // main-frequency MLP
  k_gemm<64, 64, 1, true, 8><<<NMT64, 512, 0, stream>>>(Af, NKP, Wb_f1, NKP, 23, b_f1, nullptr, nullptr, Hf, 64, 0,
                                                        nullptr, nullptr, nullptr, NMT64, NSER);
  // pred_main: transposed GEMM, coalesced stores over the series dim
  k_gemm<128, 64, 6, false, 4><<<6 * (NSER / 64), 256, 0, stream>>>(Wb_f2, 64, Hf, 64, 2, b_f2, nullptr, nullptr,
                                                                    nullptr, 0, 0, out, nullptr, nullptr, 6, 768);
}

// Round 19
// 576.195 us; speedup vs baseline: 1.0642x; 1.0642x over previous
//
#include <hip/hip_runtime.h>
#include <hip/hip_bf16.h>

typedef short short8 __attribute__((ext_vector_type(8)));
typedef short short4v __attribute__((ext_vector_type(4)));
typedef float f32x4 __attribute__((ext_vector_type(4)));
typedef __hip_bfloat16 bf16;

constexpr int NB   = 32;     // batch
constexpr int NL   = 720;    // seq len
constexpr int ND   = 862;    // channels
constexpr int NS   = 60;     // L/PERIOD
constexpr int NSER = NB * ND;    // 27584 series / GEMM rows
constexpr int NKP  = 736;    // 720 padded to 32
constexpr int NOUT = 1560;   // output rows per batch
constexpr int NMT  = 216;    // ceil(27584/128), divisible by 8 (XCD grouping)
constexpr int NMT64 = 432;   // ceil(27584/64) padded to mult of 8

__device__ __forceinline__ void gload16(const void* g, void* l) {
  __builtin_amdgcn_global_load_lds((const __attribute__((address_space(1))) void*)g,
                                   (__attribute__((address_space(3))) void*)l, 16, 0, 0);
}

// ---------------- fused init: twiddle table + weight casts + row sums ----------------

__device__ __forceinline__ void cvt_job(const float* __restrict__ src, bf16* __restrict__ dst,
                                        int rows, int cols, int rowsPad, int colsPad,
                                        int gid, int gsz) {
  int tot = rowsPad * colsPad;
  for (int i = gid; i < tot; i += gsz) {
    int r = i / colsPad, c = i - r * colsPad;
    float v = (r < rows && c < cols) ? src[r * cols + c] : 0.f;
    dst[i] = __float2bfloat16(v);
  }
}

__global__ __launch_bounds__(256) void k_init(
    const float* __restrict__ w_in_m, const float* __restrict__ w_raw_m,
    const float* __restrict__ w_in_s, const float* __restrict__ w_raw_s,
    const float* __restrict__ w_out_m, const float* __restrict__ w_out_s,
    const float* __restrict__ w_f1, const float* __restrict__ w_f2,
    double2* __restrict__ tw,
    bf16* __restrict__ Wb_in_m, bf16* __restrict__ Wb_raw_m,
    bf16* __restrict__ Wb_in_s, bf16* __restrict__ Wb_raw_s,
    bf16* __restrict__ Wb_out_m, bf16* __restrict__ Wb_out_s,
    bf16* __restrict__ Wb_f1, bf16* __restrict__ Wb_f2,
    float* __restrict__ S_in, float* __restrict__ S_raw) {
  int gid = blockIdx.x * 256 + threadIdx.x;
  int gsz = gridDim.x * 256;
  for (int j = gid; j < 720; j += gsz) {
    double a = (double)j / 360.0;          // W720^j = exp(-2*pi*i*j/720)
    tw[j] = make_double2(cospi(a), -sinpi(a));
  }
  cvt_job(w_in_m,  Wb_in_m,  512,  60, 512,   64, gid, gsz);
  cvt_job(w_raw_m, Wb_raw_m, 512, 720, 512,  NKP, gid, gsz);
  cvt_job(w_in_s,  Wb_in_s,  512,  60, 512,   64, gid, gsz);
  cvt_job(w_raw_s, Wb_raw_s, 512, 720, 512,  NKP, gid, gsz);
  cvt_job(w_out_m, Wb_out_m,  60, 1024, 64, 1024, gid, gsz);
  cvt_job(w_out_s, Wb_out_s,  60, 1024, 64, 1024, gid, gsz);
  cvt_job(w_f1,    Wb_f1,     64,  720, 64,  NKP, gid, gsz);
  cvt_job(w_f2,    Wb_f2,    720,   64, 768,  64, gid, gsz);
  for (int i = gid; i < 512; i += gsz) {
    float acc = 0.f;
    for (int j = 0; j < 60; j++) acc += w_in_m[(size_t)i * 60 + j];
    S_in[i] = acc;
  }
  for (int i = gid; i < 512; i += gsz) {
    float acc = 0.f;
    for (int j = 0; j < 720; j++) acc += w_raw_m[(size_t)i * 720 + j];
    S_raw[i] = acc;
  }
}

// ---------------- prep: stats + normalize + transposes ----------------
// 1D grid 5376 = 8 XCDs x 672; all 12 t-chunks of one (batch, d-tile) land on
// the SAME XCD consecutively -> its L2 merges partial-line writes.
// Transpose writes use tq-fast lane mapping: 15 consecutive lanes cover one
// channel row's 60-t chunk contiguously (120B AT / 240B norm runs) -> ~7x
// fewer cache-line touches per store instruction.
__global__ __launch_bounds__(256, 8) void k_prep(const float* __restrict__ x, float* __restrict__ dout,
                                                 bf16* __restrict__ AT, bf16* __restrict__ MT,
                                                 bf16* __restrict__ ST, double* __restrict__ muPart) {
  __shared__ float xs[60][65];
  int gid = blockIdx.x;
  int xcd = gid & 7, r = gid >> 3;
  int tc = r % 12, q = r / 12;
  int db = q * 8 + xcd;            // 0..447 = (d-tile)*32 + b
  int d0 = (db >> 5) * 64, b = db & 31;
  int tid = threadIdx.x;
  int t0 = tc * 60;
  // phase 1: coalesced raw load, float2-vectorized (row offsets are even)
  for (int i = tid; i < 60 * 32; i += 256) {
    int t = i >> 5, dq = i & 31, d = d0 + dq * 2;
    float2 v;
    if (d + 1 < ND) {
      v = *(const float2*)(x + ((size_t)b * NL + t0 + t) * ND + d);
    } else {
      v.x = (d < ND) ? x[((size_t)b * NL + t0 + t) * ND + d] : 0.f;
      v.y = 0.f;
    }
    xs[t][dq * 2] = v.x;
    xs[t][dq * 2 + 1] = v.y;
  }
  __syncthreads();
  // phase 2a: AT = bf16(x^T) row chunk; tq-fast mapping -> 120B contiguous runs
  for (int i = tid; i < 64 * 15; i += 256) {
    int tq = i % 15, dl = i / 15, d = d0 + dl;
    if (d < ND) {
      union { bf16 h[4]; short4v v; } u;
#pragma unroll
      for (int r2 = 0; r2 < 4; r2++) u.h[r2] = __float2bfloat16(xs[tq * 4 + r2][dl]);
      *(short4v*)(AT + (size_t)(b * ND + d) * NKP + t0 + tq * 4) = u.v;
    }
  }
  if (tid < 64) {
    int d = d0 + tid;
    if (d < ND) {
      double s = 0.0;
      for (int t = 0; t < 60; t++) s += (double)xs[t][tid];
      muPart[(size_t)(b * ND + d) * 12 + tc] = s;
    }
  }
  if (tc == 11) {  // zero pads once per (b,d)
    for (int i = tid; i < 64 * 16; i += 256) {
      int dl = i >> 4, c = 720 + (i & 15), d = d0 + dl;
      if (d < ND) AT[(size_t)(b * ND + d) * NKP + c] = __float2bfloat16(0.f);
    }
    if (tid < 64 * 4) {
      int dl = tid >> 2, s = 60 + (tid & 3), d = d0 + dl;
      if (d < ND) {
        MT[(size_t)(b * ND + d) * 64 + s] = __float2bfloat16(0.f);
        ST[(size_t)(b * ND + d) * 64 + s] = __float2bfloat16(0.f);
      }
    }
  }
  __syncthreads();
  // phase 2b: per-period stats, numpy-bit-exact f32 (sequential sums, no FMA)
  for (int i = tid; i < 64 * 5; i += 256) {
    int dl = i & 63, sp = i >> 6, d = d0 + dl;
    float v[12];
#pragma unroll
    for (int j = 0; j < 12; j++) v[j] = xs[sp * 12 + j][dl];
    float sum = 0.f;
#pragma unroll
    for (int j = 0; j < 12; j++) sum = __fadd_rn(sum, v[j]);
    float m = __fdiv_rn(sum, 12.f);
    float ss = 0.f;
#pragma unroll
    for (int j = 0; j < 12; j++) { float dj = __fsub_rn(v[j], m); ss = __fadd_rn(ss, __fmul_rn(dj, dj)); }
    float sd = __fsqrt_rn(__fdiv_rn(ss, 11.f));
    float den = __fadd_rn(sd, 1e-8f);
#pragma unroll
    for (int j = 0; j < 12; j++) xs[sp * 12 + j][dl] = __fdiv_rn(__fsub_rn(v[j], m), den);
    if (d < ND) {
      MT[(size_t)(b * ND + d) * 64 + tc * 5 + sp] = __float2bfloat16(m);
      ST[(size_t)(b * ND + d) * 64 + tc * 5 + sp] = __float2bfloat16(sd);
    }
  }
  __syncthreads();
  // phase 3: norm^T chunk; tq-fast mapping -> 240B contiguous runs
  float* nt = dout + ((size_t)b * NOUT + 720) * ND;
  for (int i = tid; i < 64 * 15; i += 256) {
    int tq = i % 15, dl = i / 15, d = d0 + dl;
    if (d < ND) {
      float4 f;
      f.x = xs[tq * 4 + 0][dl]; f.y = xs[tq * 4 + 1][dl];
      f.z = xs[tq * 4 + 2][dl]; f.w = xs[tq * 4 + 3][dl];
      *(float4*)(nt + (size_t)d * 720 + t0 + tq * 4) = f;
    }
  }
}

__global__ __launch_bounds__(256) void k_mured(const double* __restrict__ muPart, float* __restrict__ mu) {
  int ser = blockIdx.x * 256 + threadIdx.x;
  if (ser < NSER) {
    const double* p = muPart + (size_t)ser * 12;
    double s = 0.0;
#pragma unroll
    for (int j = 0; j < 12; j++) s += p[j];
    mu[ser] = (float)(s / 720.0);
  }
}

// ---------------- fp64 FFT (720 = 16*9*5), 2 real series packed per block ----------------
// 128 threads/block (round-17 structural floor: ~43% occupancy, issue-bound).
#define PIDX(i) ((i) + ((i) >> 4))

__device__ __forceinline__ void dft3(double x0r, double x0i, double x1r, double x1i,
                                     double x2r, double x2i, double s3,
                                     double& y0r, double& y0i, double& y1r, double& y1i,
                                     double& y2r, double& y2i) {
  double ur = x1r + x2r, ui = x1i + x2i;
  double wr = x1r - x2r, wi = x1i - x2i;
  double mr = x0r - 0.5 * ur, mi = x0i - 0.5 * ui;
  y0r = x0r + ur;      y0i = x0i + ui;
  y1r = mr + s3 * wi;  y1i = mi - s3 * wr;
  y2r = mr - s3 * wi;  y2i = mi + s3 * wr;
}

__device__ __forceinline__ void dft4(double x0r, double x0i, double x1r, double x1i,
                                     double x2r, double x2i, double x3r, double x3i,
                                     double& y0r, double& y0i, double& y1r, double& y1i,
                                     double& y2r, double& y2i, double& y3r, double& y3i) {
  double a0r = x0r + x2r, a0i = x0i + x2i;
  double a1r = x0r - x2r, a1i = x0i - x2i;
  double a2r = x1r + x3r, a2i = x1i + x3i;
  double a3r = x1r - x3r, a3i = x1i - x3i;
  y0r = a0r + a2r; y0i = a0i + a2i;
  y2r = a0r - a2r; y2i = a0i - a2i;
  y1r = a1r + a3i; y1i = a1i - a3r;   // + (-i)*a3
  y3r = a1r - a3i; y3i = a1i + a3r;   // + (+i)*a3
}

__device__ __forceinline__ void cmulw(double& xr, double& xi, double2 w) {
  double r = xr * w.x - xi * w.y;
  double i = xr * w.y + xi * w.x;
  xr = r; xi = i;
}

__global__ __launch_bounds__(128) void k_fft(const float* __restrict__ dout, const double2* __restrict__ twg,
                                             unsigned short* __restrict__ selK, float* __restrict__ selA,
                                             float* __restrict__ selB, int* __restrict__ selCnt,
                                             int blkoff) {
  __shared__ double re[765], im[765];
  int ser0 = 2 * (blockIdx.x + blkoff);    // pairs never cross a batch (862 channels = even)
  int b = ser0 / ND, d0 = ser0 - b * ND;
  int tid = threadIdx.x;
  double s3 = -twg[240].y;                                 // sin(2*pi/3)
  double2 w9_1 = twg[80], w9_2 = twg[160], w9_4 = twg[320];
  double2 w16_1 = twg[45], w16_2 = twg[90], w16_3 = twg[135];
  double2 w16_4 = twg[180], w16_6 = twg[270], w16_9 = twg[405];
  double w5r[5], w5i[5];
#pragma unroll
  for (int j = 0; j < 5; j++) { double2 t = twg[144 * j]; w5r[j] = t.x; w5i[j] = t.y; }

  const float* row0 = dout + ((size_t)b * NOUT + 720) * ND + (size_t)d0 * 720;
  for (int n = tid; n < 720; n += 128) {
    re[PIDX(n)] = (double)row0[n];
    im[PIDX(n)] = (double)row0[720 + n];
  }
  __syncthreads();
  // step 1: 144 DFT-5 (stride 144)
  for (int task = tid; task < 144; task += 128) {
    double ar[5], ai[5], orr[5], oi[5];
#pragma unroll
    for (int n3 = 0; n3 < 5; n3++) { int p = PIDX(task + 144 * n3); ar[n3] = re[p]; ai[n3] = im[p]; }
    orr[0] = ar[0] + ar[1] + ar[2] + ar[3] + ar[4];
    oi[0]  = ai[0] + ai[1] + ai[2] + ai[3] + ai[4];
#pragma unroll
    for (int k3 = 1; k3 < 5; k3++) {
      double sr = ar[0], si = ai[0];
#pragma unroll
      for (int n3 = 1; n3 < 5; n3++) {
        int j = (n3 * k3) % 5;
        sr += ar[n3] * w5r[j] - ai[n3] * w5i[j];
        si += ar[n3] * w5i[j] + ai[n3] * w5r[j];
      }
      orr[k3] = sr; oi[k3] = si;
    }
#pragma unroll
    for (int k3 = 0; k3 < 5; k3++) { int p = PIDX(task + 144 * k3); re[p] = orr[k3]; im[p] = oi[k3]; }
  }
  __syncthreads();
  // step 2: 80 DFT-9 (stride 16) with pre-twiddle; 9 = 3x3 butterfly
  if (tid < 80) {
    int task = tid;
    int n1 = task & 15, k3 = task >> 4;
    double xr[9], xi[9];
#pragma unroll
    for (int n2 = 0; n2 < 9; n2++) {
      int p = PIDX(n1 + 16 * n2 + 144 * k3);
      double a = re[p], bb = im[p];
      double2 w = twg[16 * n2 * k3];        // < 720 always
      xr[n2] = a * w.x - bb * w.y;
      xi[n2] = a * w.y + bb * w.x;
    }
    double tr[3][3], ti[3][3];
#pragma unroll
    for (int a = 0; a < 3; a++)
      dft3(xr[a], xi[a], xr[a + 3], xi[a + 3], xr[a + 6], xi[a + 6], s3,
           tr[a][0], ti[a][0], tr[a][1], ti[a][1], tr[a][2], ti[a][2]);
    cmulw(tr[1][1], ti[1][1], w9_1);
    cmulw(tr[1][2], ti[1][2], w9_2);
    cmulw(tr[2][1], ti[2][1], w9_2);
    cmulw(tr[2][2], ti[2][2], w9_4);
#pragma unroll
    for (int c = 0; c < 3; c++) {
      double y0r, y0i, y1r, y1i, y2r, y2i;
      dft3(tr[0][c], ti[0][c], tr[1][c], ti[1][c], tr[2][c], ti[2][c], s3,
           y0r, y0i, y1r, y1i, y2r, y2i);
      int p0 = PIDX(n1 + 16 * (c + 0) + 144 * k3);
      int p1 = PIDX(n1 + 16 * (c + 3) + 144 * k3);
      int p2 = PIDX(n1 + 16 * (c + 6) + 144 * k3);
      re[p0] = y0r; im[p0] = y0i;
      re[p1] = y1r; im[p1] = y1i;
      re[p2] = y2r; im[p2] = y2i;
    }
  }
  __syncthreads();
  // step 3: 45 DFT-16 with pre-twiddle; 16 = 4x4 butterfly; write Z linear
  double vr[16], vi[16];
  int k2 = 0, k3 = 0;
  bool act = tid < 45;
  if (act) {
    k2 = tid % 9; k3 = tid / 9;
    int base = 16 * k2 + 144 * k3, tf = k3 + 5 * k2;
    int idx = 0;
#pragma unroll
    for (int n1 = 0; n1 < 16; n1++) {
      int p = PIDX(base + n1);
      double a = re[p], bb = im[p];
      double2 w = twg[idx];                 // idx = n1*tf <= 660
      vr[n1] = a * w.x - bb * w.y;
      vi[n1] = a * w.y + bb * w.x;
      idx += tf;
    }
  }
  __syncthreads();  // all reads done before overwriting with Z
  if (act) {
    int kbase = k3 + 5 * k2;
    double t1r[4][4], t1i[4][4];
#pragma unroll
    for (int a = 0; a < 4; a++)
      dft4(vr[a], vi[a], vr[a + 4], vi[a + 4], vr[a + 8], vi[a + 8], vr[a + 12], vi[a + 12],
           t1r[a][0], t1i[a][0], t1r[a][1], t1i[a][1],
           t1r[a][2], t1i[a][2], t1r[a][3], t1i[a][3]);
    cmulw(t1r[1][1], t1i[1][1], w16_1);
    cmulw(t1r[1][2], t1i[1][2], w16_2);
    cmulw(t1r[1][3], t1i[1][3], w16_3);
    cmulw(t1r[2][1], t1i[2][1], w16_2);
    cmulw(t1r[2][2], t1i[2][2], w16_4);
    cmulw(t1r[2][3], t1i[2][3], w16_6);
    cmulw(t1r[3][1], t1i[3][1], w16_3);
    cmulw(t1r[3][2], t1i[3][2], w16_6);
    cmulw(t1r[3][3], t1i[3][3], w16_9);
#pragma unroll
    for (int c = 0; c < 4; c++) {
      double y0r, y0i, y1r, y1i, y2r, y2i, y3r, y3i;
      dft4(t1r[0][c], t1i[0][c], t1r[1][c], t1i[1][c],
           t1r[2][c], t1i[2][c], t1r[3][c], t1i[3][c],
           y0r, y0i, y1r, y1i, y2r, y2i, y3r, y3i);
      re[kbase + 45 * (c + 0)]  = y0r; im[kbase + 45 * (c + 0)]  = y0i;
      re[kbase + 45 * (c + 4)]  = y1r; im[kbase + 45 * (c + 4)]  = y1i;
      re[kbase + 45 * (c + 8)]  = y2r; im[kbase + 45 * (c + 8)]  = y2i;
      re[kbase + 45 * (c + 12)] = y3r; im[kbase + 45 * (c + 12)] = y3i;
    }
  }
  __syncthreads();
  // wave 0 -> series A, wave 1 -> series B (concurrent selection).
  int lane = tid & 63, wv = tid >> 6;
  unsigned long long key[6];
#pragma unroll
  for (int j = 0; j < 6; j++) {
    int k = lane + 64 * j;
    if (k <= 360) {
      int mk = (k == 0) ? 0 : 720 - k;
      double zr = re[k], zi = im[k], wr = re[mk], wi = im[mk];
      double m2;
      if (wv == 0) {
        double ra = 0.5 * (zr + wr), ia = 0.5 * (zi - wi);
        m2 = ra * ra + ia * ia;
      } else {
        double rb = 0.5 * (zi + wi), ib = 0.5 * (wr - zr);
        m2 = rb * rb + ib * ib;
      }
      key[j] = (__double_as_longlong(m2) & ~0x1FFull) | (unsigned long long)(511 - k);
    } else {
      key[j] = 0ull;
    }
  }
#define CSWP(a, b) { unsigned long long ka = key[a], kb = key[b]; \
                     key[a] = ka > kb ? ka : kb; key[b] = ka > kb ? kb : ka; }
  CSWP(0,1) CSWP(1,2) CSWP(2,3) CSWP(3,4) CSWP(4,5)
  CSWP(0,1) CSWP(1,2) CSWP(2,3) CSWP(3,4)
  CSWP(0,1) CSWP(1,2) CSWP(2,3)
  CSWP(0,1) CSWP(1,2)
  CSWP(0,1)
#undef CSWP
  {
    int ser = ser0 + wv;
    bool isB = (wv == 1);
    int used = 0, cnt = 0;
    while (used < 30) {
      unsigned long long m = key[0];
#pragma unroll
      for (int off = 32; off; off >>= 1) {
        unsigned long long o = __shfl_xor(m, off);
        m = (o > m) ? o : m;
      }
      int bk = 511 - (int)(m & 0x1FF);
      int w = (bk == 0 || bk == 360) ? 1 : 2;
      int take = (30 - used < w) ? (30 - used) : w;
      bool own = (key[0] == m);     // keys globally unique -> exactly one owner
      if (own) {
        int mk = (bk == 0) ? 0 : 720 - bk;
        double zr = re[bk], zi = im[bk], wr = re[mk], wi = im[mk];
        double cr, ci;
        if (!isB) { cr = 0.5 * (zr + wr); ci = 0.5 * (zi - wi); }
        else      { cr = 0.5 * (zi + wi); ci = 0.5 * (wr - zr); }
        double scale = (double)take / 720.0;
        selK[(size_t)ser * 32 + cnt] = (unsigned short)bk;
        selA[(size_t)ser * 32 + cnt] = (float)(scale * cr);
        selB[(size_t)ser * 32 + cnt] = (float)(scale * ci);
      }
      key[0] = own ? key[1] : key[0];
      key[1] = own ? key[2] : key[1];
      key[2] = own ? key[3] : key[2];
      key[3] = own ? key[4] : key[3];
      key[4] = own ? key[5] : key[4];
      key[5] = own ? 0ull   : key[5];
      used += take; cnt++;
    }
    if (lane == 0) selCnt[ser] = cnt;
  }
}

// ---------------- reconstruction: x_f, residual, bf16 A_f ----------------
// grid (14, 3, 32): 64 channels x 240 t per block; 12-wide t-tiles per wave.
__global__ __launch_bounds__(256, 6) void k_recon(float* __restrict__ dout, const unsigned short* __restrict__ selK,
                                                  const float* __restrict__ selA, const float* __restrict__ selB,
                                                  const int* __restrict__ selCnt, const double2* __restrict__ twg,
                                                  bf16* __restrict__ Af) {
  __shared__ unsigned short kk[64][31];
  __shared__ float AAc[64][31], BBc[64][31];
  __shared__ int cc[64];
  __shared__ float2 tbl[720];
  int b = blockIdx.z, tch = blockIdx.y, d0 = blockIdx.x * 64, tid = threadIdx.x;
  for (int j = tid; j < 720; j += 256) { double2 w = twg[j]; tbl[j] = make_float2((float)w.x, (float)w.y); }
  for (int i = tid; i < 64 * 30; i += 256) {
    int dl = i / 30, j = i - dl * 30, d = d0 + dl;
    if (d < ND) {
      size_t o = (size_t)(b * ND + d) * 32 + j;
      kk[dl][j] = selK[o]; AAc[dl][j] = selA[o]; BBc[dl][j] = selB[o];
    }
  }
  if (tid < 64) cc[tid] = (d0 + tid < ND) ? selCnt[b * ND + d0 + tid] : 0;
  if (tch == 0) {  // zero-pad Af cols 720..735 once
    for (int i = tid; i < 64 * 16; i += 256) {
      int r = i >> 4, c = 720 + (i & 15), dd = d0 + r;
      if (dd < ND) Af[(size_t)(b * ND + dd) * NKP + c] = __float2bfloat16(0.f);
    }
  }
  __syncthreads();
  int dl = tid & 63, tb = tid >> 6;
  int d = d0 + dl;
  bool valid = d < ND;
  const float* nrow = dout + ((size_t)b * NOUT + 720) * ND + (size_t)(valid ? d : 0) * 720;
  bf16* afrow = Af + (size_t)(b * ND + (valid ? d : 0)) * NKP;
  int n = cc[dl];
#pragma unroll
  for (int m = 0; m < 5; m++) {
    int t0 = tch * 240 + tb * 12 + m * 48;
    float a[12];
#pragma unroll
    for (int r = 0; r < 12; r++) a[r] = 0.f;
    for (int j = 0; j < n; j++) {
      int k = kk[dl][j];
      float Aj = AAc[dl][j], Bj = BBc[dl][j];
      float2 w = tbl[k];                       // e^{-i*2pi*k/720}
      float2 c = tbl[(k * t0) % 720];          // e^{-i*2pi*k*t0/720}
#pragma unroll
      for (int r = 0; r < 12; r++) {
        a[r] = fmaf(Aj, c.x, fmaf(Bj, c.y, a[r]));
        if (r < 11) {
          float nx = c.x * w.x - c.y * w.y;
          float ny = c.x * w.y + c.y * w.x;
          c.x = nx; c.y = ny;
        }
      }
    }
    if (valid) {
      union { bf16 h[12]; short4v v[3]; } u;
#pragma unroll
      for (int r = 0; r < 12; r++) u.h[r] = __float2bfloat16(a[r]);
      *(short4v*)(afrow + t0 + 0) = u.v[0];
      *(short4v*)(afrow + t0 + 4) = u.v[1];
      *(short4v*)(afrow + t0 + 8) = u.v[2];
      float4 n0 = *(const float4*)(nrow + t0 + 0);
      float4 n1 = *(const float4*)(nrow + t0 + 4);
      float4 n2 = *(const float4*)(nrow + t0 + 8);
      const float nv[12] = {n0.x, n0.y, n0.z, n0.w, n1.x, n1.y, n1.z, n1.w,
                            n2.x, n2.y, n2.z, n2.w};
#pragma unroll
      for (int r = 0; r < 12; r++)
        dout[((size_t)b * NOUT + (t0 + r)) * ND + d] = nv[r] - a[r];
    }
  }
}

// ---------------- MFMA GEMM, C = A(Mrows x K) * W(N x K)^T ----------------
// 2-phase double-buffered K-loop; BM/WAVES template picks tiling.
template <int BM, int BN, int MODE, bool XCD, int WAVES>
__global__ __launch_bounds__(WAVES * 64) void k_gemm(const bf16* __restrict__ A, int lda,
                                              const bf16* __restrict__ W, int ldb, int Ktiles,
                                              const float* __restrict__ bias, const float* __restrict__ rowMu,
                                              const float* __restrict__ colS, bf16* __restrict__ Hout, int hldc,
                                              int hoff, float* __restrict__ dout, const float* __restrict__ wgt,
                                              const float* __restrict__ meanall, int Mtiles, int Mrows) {
  __shared__ bf16 sA[2 * BM * 32];
  __shared__ bf16 sB[2 * BN * 32];
  const int M = Mrows;
  int Ntiles = gridDim.x / Mtiles;
  int bid = blockIdx.x;
  int mt, nt;
  if constexpr (XCD) {  // same-A blocks 8 apart (same XCD), consecutive in dispatch
    int xg = bid & 7, q = bid >> 3;
    nt = q % Ntiles;
    mt = (q / Ntiles) * 8 + xg;
  } else {
    mt = bid % Mtiles; nt = bid / Mtiles;
  }
  int tid = threadIdx.x, wave = tid >> 6, lane = tid & 63;
  constexpr int RN = BN / 32;
  constexpr int MI = (2 * BM) / (16 * WAVES);
  static_assert(MI >= 1, "bad tiling");
  int wr = (wave >> 1) * (16 * MI);
  int wc = (wave & 1) * (BN / 2);
  f32x4 zero = {0.f, 0.f, 0.f, 0.f};
  f32x4 acc[MI][RN];
#pragma unroll
  for (int i = 0; i < MI; i++)
#pragma unroll
    for (int j = 0; j < RN; j++) acc[i][j] = zero;
  int rl = lane >> 2;             // row within 16-row group
  int cb = (lane & 3) * 8;        // k-element offset of this lane's 16B

  constexpr int ACH = BM / 16, BCH = BN / 16;
  auto stage = [&](int buf, int kt) {
    for (int c = wave; c < ACH + BCH; c += WAVES) {
      if (c < ACH) {
        int grow = mt * BM + c * 16 + rl;
        if (grow > M - 1) grow = M - 1;
        gload16(A + (size_t)grow * lda + kt * 32 + cb,
                (char*)sA + (size_t)buf * (BM * 64) + (size_t)(c * 16) * 64);
      } else {
        int i = c - ACH;
        int gn = nt * BN + i * 16 + rl;
        gload16(W + (size_t)gn * ldb + kt * 32 + cb,
                (char*)sB + (size_t)buf * (BN * 64) + (size_t)(i * 16) * 64);
      }
    }
  };

  stage(0, 0);
  __syncthreads();
  for (int kt = 0; kt < Ktiles; kt++) {
    int cur = kt & 1;
    if (kt + 1 < Ktiles) stage(cur ^ 1, kt + 1);   // prefetch next tile
    int r16 = lane & 15, kb = (lane >> 4) * 16;
    const char* baseA = (const char*)sA + (size_t)cur * (BM * 64);
    const char* baseB = (const char*)sB + (size_t)cur * (BN * 64);
    short8 av[MI], bv[RN];
#pragma unroll
    for (int mi = 0; mi < MI; mi++)
      av[mi] = *(const short8*)(baseA + (size_t)(wr + mi * 16 + r16) * 64 + kb);
#pragma unroll
    for (int ni = 0; ni < RN; ni++)
      bv[ni] = *(const short8*)(baseB + (size_t)(wc + ni * 16 + r16) * 64 + kb);
#pragma unroll
    for (int mi = 0; mi < MI; mi++)
#pragma unroll
      for (int ni = 0; ni < RN; ni++)
        acc[mi][ni] = __builtin_amdgcn_mfma_f32_16x16x32_bf16(av[mi], bv[ni], acc[mi][ni], 0, 0, 0);
    __syncthreads();   // drains prefetch + guards buffer reuse
  }
  int cr = (lane >> 4) * 4, ccol = lane & 15;
#pragma unroll
  for (int mi = 0; mi < MI; mi++) {
#pragma unroll
    for (int ni = 0; ni < RN; ni++) {
      int gm0 = mt * BM + wr + mi * 16 + cr;
      int gn = nt * BN + wc + ni * 16 + ccol;
      f32x4 c = acc[mi][ni];
      if constexpr (MODE == 0 || MODE == 1) {
        float bb = bias[gn];
        float cs = (MODE == 0) ? colS[gn] : 0.f;
#pragma unroll
        for (int r = 0; r < 4; r++) {
          int gm = gm0 + r;
          if (gm < M) {
            float v = c[r] + bb;
            if constexpr (MODE == 0) v = tanhf(v - rowMu[gm] * cs);
            else v = fmaxf(v, 0.f);
            Hout[(size_t)gm * hldc + hoff + gn] = __float2bfloat16(v);
          }
        }
      } else if constexpr (MODE == 2 || MODE == 3) {
        if (gn < 60) {
          float bb = bias[gn];
#pragma unroll
          for (int r = 0; r < 4; r++) {
            int gm = gm0 + r;
            if (gm < M) {
              int bI = gm / ND, dd = gm - bI * ND;
              float v;
              if constexpr (MODE == 2) v = (c[r] + bb) * wgt[dd] + meanall[gm] * wgt[ND + dd];
              else v = fmaxf(c[r] + bb, 0.f);
              constexpr int rowoff = (MODE == 2) ? 1440 : 1500;
              dout[((size_t)bI * NOUT + rowoff + gn) * ND + dd] = v;
            }
          }
        }
      } else {  // MODE 6: rows = f2 output index p, cols = series (coalesced)
        int bI = gn / ND, dd = gn - bI * ND;
#pragma unroll
        for (int r = 0; r < 4; r++) {
          int pp = gm0 + r;
          if (pp < 720) {
            dout[((size_t)bI * NOUT + 720 + pp) * ND + dd] = c[r] + bias[pp];
          }
        }
      }
    }
  }
}

// ---------------- launcher ----------------

extern "C" void kernel_launch(void* const* d_in, const int* in_sizes, int n_in,
                              void* d_out, int out_size, void* d_ws, size_t ws_size,
                              hipStream_t stream) {
  (void)in_sizes; (void)n_in; (void)out_size; (void)ws_size;
  const float* x       = (const float*)d_in[0];
  const float* w_in_m  = (const float*)d_in[1];
  const float* b_in_m  = (const float*)d_in[2];
  const float* w_raw_m = (const float*)d_in[3];
  const float* b_raw_m = (const float*)d_in[4];
  const float* w_out_m = (const float*)d_in[5];
  const float* b_out_m = (const float*)d_in[6];
  const float* w_in_s  = (const float*)d_in[7];
  const float* b_in_s  = (const float*)d_in[8];
  const float* w_raw_s = (const float*)d_in[9];
  const float* b_raw_s = (const float*)d_in[10];
  const float* w_out_s = (const float*)d_in[11];
  const float* b_out_s = (const float*)d_in[12];
  const float* w_f1    = (const float*)d_in[13];
  const float* b_f1    = (const float*)d_in[14];
  const float* w_f2    = (const float*)d_in[15];
  const float* b_f2    = (const float*)d_in[16];
  const float* wgt     = (const float*)d_in[17];
  float* out = (float*)d_out;

  char* p = (char*)d_ws;
  size_t off = 0;
  auto carve = [&](size_t bytes) { char* r = p + off; off += (bytes + 255) & ~(size_t)255; return r; };

  bf16* AT      = (bf16*)carve((size_t)NSER * NKP * 2);
  bf16* Af      = (bf16*)carve((size_t)NSER * NKP * 2);
  bf16* MT      = (bf16*)carve((size_t)NSER * 64 * 2);
  bf16* ST      = (bf16*)carve((size_t)NSER * 64 * 2);
  bf16* Hf      = (bf16*)carve((size_t)NSER * 64 * 2);
  float* mu     = (float*)carve((size_t)NSER * 4);
  double* muPart = (double*)carve((size_t)NSER * 12 * 8);
  double2* tw   = (double2*)carve(720 * sizeof(double2));
  bf16* Wb_in_m  = (bf16*)carve((size_t)512 * 64 * 2);
  bf16* Wb_raw_m = (bf16*)carve((size_t)512 * NKP * 2);
  bf16* Wb_in_s  = (bf16*)carve((size_t)512 * 64 * 2);
  bf16* Wb_raw_s = (bf16*)carve((size_t)512 * NKP * 2);
  bf16* Wb_out_m = (bf16*)carve((size_t)64 * 1024 * 2);
  bf16* Wb_out_s = (bf16*)carve((size_t)64 * 1024 * 2);
  bf16* Wb_f1    = (bf16*)carve((size_t)64 * NKP * 2);
  bf16* Wb_f2    = (bf16*)carve((size_t)768 * 64 * 2);
  float* S_in    = (float*)carve(512 * 4);
  float* S_raw   = (float*)carve(512 * 4);
  // sel arrays are dead before H is first written -> overlay H on them
  char* selBase = p + off;
  unsigned short* selK = (unsigned short*)carve((size_t)NSER * 32 * 2);
  float* selA   = (float*)carve((size_t)NSER * 32 * 4);
  float* selB   = (float*)carve((size_t)NSER * 32 * 4);
  int* selCnt   = (int*)carve((size_t)NSER * 4);
  bf16* H = (bf16*)selBase;  // 27584 x 1024 bf16 (56.5 MB), reuses sel region

  k_init<<<512, 256, 0, stream>>>(w_in_m, w_raw_m, w_in_s, w_raw_s, w_out_m, w_out_s, w_f1, w_f2,
                                  tw, Wb_in_m, Wb_raw_m, Wb_in_s, Wb_raw_s, Wb_out_m, Wb_out_s,
                                  Wb_f1, Wb_f2, S_in, S_raw);

  k_prep<<<14 * 12 * 32, 256, 0, stream>>>(x, out, AT, MT, ST, muPart);
  k_mured<<<(NSER + 255) / 256, 256, 0, stream>>>(muPart, mu);
  k_fft<<<NSER / 4, 128, 0, stream>>>(out, tw, selK, selA, selB, selCnt, 0);
  k_fft<<<NSER / 4, 128, 0, stream>>>(out, tw, selK, selA, selB, selCnt, NSER / 4);
  k_recon<<<dim3(14, 3, 32), 256, 0, stream>>>(out, selK, selA, selB, selCnt, tw, Af);

  // mean MLP
  k_gemm<128, 128, 0, true, 8><<<NMT * 4, 512, 0, stream>>>(MT, 64, Wb_in_m, 64, 2, b_in_m, mu, S_in, H, 1024, 0,
                                                            nullptr, nullptr, nullptr, NMT, NSER);
  k_gemm<128, 128, 0, true, 8><<<NMT * 4, 512, 0, stream>>>(AT, NKP, Wb_raw_m, NKP, 23, b_raw_m, mu, S_raw, H, 1024, 512,
                                                            nullptr, nullptr, nullptr, NMT, NSER);
  k_gemm<64, 64, 2, true, 8><<<NMT64, 512, 0, stream>>>(H, 1024, Wb_out_m, 1024, 32, b_out_m, nullptr, nullptr,
                                                        nullptr, 0, 0, out, wgt, mu, NMT64, NSER);
  // std MLP (reuses H)
  k_gemm<128, 128, 1, true, 8><<<NMT * 4, 512, 0, stream>>>(ST, 64, Wb_in_s, 64, 2, b_in_s, nullptr, nullptr, H, 1024, 0,
                                                            nullptr, nullptr, nullptr, NMT, NSER);
  k_gemm<128, 128, 1, true, 8><<<NMT * 4, 512, 0, stream>>>(AT, NKP, Wb_raw_s, NKP, 23, b_raw_s, nullptr, nullptr, H, 1024, 512,
                                                            nullptr, nullptr, nullptr, NMT, NSER);
  k_gemm<64, 64, 3, true, 8><<<NMT64, 512, 0, stream>>>(H, 1024, Wb_out_s, 1024, 32, b_out_s, nullptr, nullptr,
                                                        nullptr, 0, 0, out, nullptr, nullptr, NMT64, NSER);
  // main-frequency MLP
  k_gemm<64, 64, 1, true, 8><<<NMT64, 512, 0, stream>>>(Af, NKP, Wb_f1, NKP, 23, b_f1, nullptr, nullptr, Hf, 64, 0,
                                                        nullptr, nullptr, nullptr, NMT64, NSER);
  // pred_main: transposed GEMM, coalesced stores over the series dim
  k_gemm<128, 64, 6, false, 4><<<6 * (NSER / 64), 256, 0, stream>>>(Wb_f2, 64, Hf, 64, 2, b_f2, nullptr, nullptr,
                                                                    nullptr, 0, 0, out, nullptr, nullptr, 6, 768);
}

// Round 20
// 570.580 us; speedup vs baseline: 1.0747x; 1.0098x over previous
//
#include <hip/hip_runtime.h>
#include <hip/hip_bf16.h>

typedef short short8 __attribute__((ext_vector_type(8)));
typedef short short4v __attribute__((ext_vector_type(4)));
typedef float f32x4 __attribute__((ext_vector_type(4)));
typedef __hip_bfloat16 bf16;

constexpr int NB   = 32;     // batch
constexpr int NL   = 720;    // seq len
constexpr int ND   = 862;    // channels
constexpr int NS   = 60;     // L/PERIOD
constexpr int NSER = NB * ND;    // 27584 series / GEMM rows
constexpr int NKP  = 736;    // 720 padded to 32
constexpr int NOUT = 1560;   // output rows per batch
constexpr int NMT  = 216;    // ceil(27584/128), divisible by 8 (XCD grouping)
constexpr int NMT64 = 432;   // ceil(27584/64) padded to mult of 8

__device__ __forceinline__ void gload16(const void* g, void* l) {
  __builtin_amdgcn_global_load_lds((const __attribute__((address_space(1))) void*)g,
                                   (__attribute__((address_space(3))) void*)l, 16, 0, 0);
}

// ---------------- fused init: twiddle table + weight casts + row sums ----------------

__device__ __forceinline__ void cvt_job(const float* __restrict__ src, bf16* __restrict__ dst,
                                        int rows, int cols, int rowsPad, int colsPad,
                                        int gid, int gsz) {
  int tot = rowsPad * colsPad;
  for (int i = gid; i < tot; i += gsz) {
    int r = i / colsPad, c = i - r * colsPad;
    float v = (r < rows && c < cols) ? src[r * cols + c] : 0.f;
    dst[i] = __float2bfloat16(v);
  }
}

__global__ __launch_bounds__(256) void k_init(
    const float* __restrict__ w_in_m, const float* __restrict__ w_raw_m,
    const float* __restrict__ w_in_s, const float* __restrict__ w_raw_s,
    const float* __restrict__ w_out_m, const float* __restrict__ w_out_s,
    const float* __restrict__ w_f1, const float* __restrict__ w_f2,
    double2* __restrict__ tw,
    bf16* __restrict__ Wb_in_m, bf16* __restrict__ Wb_raw_m,
    bf16* __restrict__ Wb_in_s, bf16* __restrict__ Wb_raw_s,
    bf16* __restrict__ Wb_out_m, bf16* __restrict__ Wb_out_s,
    bf16* __restrict__ Wb_f1, bf16* __restrict__ Wb_f2,
    float* __restrict__ S_in, float* __restrict__ S_raw) {
  int gid = blockIdx.x * 256 + threadIdx.x;
  int gsz = gridDim.x * 256;
  for (int j = gid; j < 720; j += gsz) {
    double a = (double)j / 360.0;          // W720^j = exp(-2*pi*i*j/720)
    tw[j] = make_double2(cospi(a), -sinpi(a));
  }
  cvt_job(w_in_m,  Wb_in_m,  512,  60, 512,   64, gid, gsz);
  cvt_job(w_raw_m, Wb_raw_m, 512, 720, 512,  NKP, gid, gsz);
  cvt_job(w_in_s,  Wb_in_s,  512,  60, 512,   64, gid, gsz);
  cvt_job(w_raw_s, Wb_raw_s, 512, 720, 512,  NKP, gid, gsz);
  cvt_job(w_out_m, Wb_out_m,  60, 1024, 64, 1024, gid, gsz);
  cvt_job(w_out_s, Wb_out_s,  60, 1024, 64, 1024, gid, gsz);
  cvt_job(w_f1,    Wb_f1,     64,  720, 64,  NKP, gid, gsz);
  cvt_job(w_f2,    Wb_f2,    720,   64, 768,  64, gid, gsz);
  for (int i = gid; i < 512; i += gsz) {
    float acc = 0.f;
    for (int j = 0; j < 60; j++) acc += w_in_m[(size_t)i * 60 + j];
    S_in[i] = acc;
  }
  for (int i = gid; i < 512; i += gsz) {
    float acc = 0.f;
    for (int j = 0; j < 720; j++) acc += w_raw_m[(size_t)i * 720 + j];
    S_raw[i] = acc;
  }
}

// ---------------- prep: stats + normalize + transposes ----------------
// 1D grid 5376 = 8 XCDs x 672; all 12 t-chunks of one (batch, d-tile) land on
// the SAME XCD consecutively -> its L2 merges partial-line writes.
// Transpose writes use tq-fast lane mapping (120B/240B contiguous runs).
__global__ __launch_bounds__(256, 8) void k_prep(const float* __restrict__ x, float* __restrict__ dout,
                                                 bf16* __restrict__ AT, bf16* __restrict__ MT,
                                                 bf16* __restrict__ ST, double* __restrict__ muPart) {
  __shared__ float xs[60][65];
  int gid = blockIdx.x;
  int xcd = gid & 7, r = gid >> 3;
  int tc = r % 12, q = r / 12;
  int db = q * 8 + xcd;            // 0..447 = (d-tile)*32 + b
  int d0 = (db >> 5) * 64, b = db & 31;
  int tid = threadIdx.x;
  int t0 = tc * 60;
  // phase 1: coalesced raw load, float2-vectorized (row offsets are even)
  for (int i = tid; i < 60 * 32; i += 256) {
    int t = i >> 5, dq = i & 31, d = d0 + dq * 2;
    float2 v;
    if (d + 1 < ND) {
      v = *(const float2*)(x + ((size_t)b * NL + t0 + t) * ND + d);
    } else {
      v.x = (d < ND) ? x[((size_t)b * NL + t0 + t) * ND + d] : 0.f;
      v.y = 0.f;
    }
    xs[t][dq * 2] = v.x;
    xs[t][dq * 2 + 1] = v.y;
  }
  __syncthreads();
  // phase 2a: AT = bf16(x^T) row chunk; tq-fast mapping -> 120B contiguous runs
  for (int i = tid; i < 64 * 15; i += 256) {
    int tq = i % 15, dl = i / 15, d = d0 + dl;
    if (d < ND) {
      union { bf16 h[4]; short4v v; } u;
#pragma unroll
      for (int r2 = 0; r2 < 4; r2++) u.h[r2] = __float2bfloat16(xs[tq * 4 + r2][dl]);
      *(short4v*)(AT + (size_t)(b * ND + d) * NKP + t0 + tq * 4) = u.v;
    }
  }
  if (tid < 64) {
    int d = d0 + tid;
    if (d < ND) {
      double s = 0.0;
      for (int t = 0; t < 60; t++) s += (double)xs[t][tid];
      muPart[(size_t)(b * ND + d) * 12 + tc] = s;
    }
  }
  if (tc == 11) {  // zero pads once per (b,d)
    for (int i = tid; i < 64 * 16; i += 256) {
      int dl = i >> 4, c = 720 + (i & 15), d = d0 + dl;
      if (d < ND) AT[(size_t)(b * ND + d) * NKP + c] = __float2bfloat16(0.f);
    }
    if (tid < 64 * 4) {
      int dl = tid >> 2, s = 60 + (tid & 3), d = d0 + dl;
      if (d < ND) {
        MT[(size_t)(b * ND + d) * 64 + s] = __float2bfloat16(0.f);
        ST[(size_t)(b * ND + d) * 64 + s] = __float2bfloat16(0.f);
      }
    }
  }
  __syncthreads();
  // phase 2b: per-period stats, numpy-bit-exact f32 (sequential sums, no FMA)
  for (int i = tid; i < 64 * 5; i += 256) {
    int dl = i & 63, sp = i >> 6, d = d0 + dl;
    float v[12];
#pragma unroll
    for (int j = 0; j < 12; j++) v[j] = xs[sp * 12 + j][dl];
    float sum = 0.f;
#pragma unroll
    for (int j = 0; j < 12; j++) sum = __fadd_rn(sum, v[j]);
    float m = __fdiv_rn(sum, 12.f);
    float ss = 0.f;
#pragma unroll
    for (int j = 0; j < 12; j++) { float dj = __fsub_rn(v[j], m); ss = __fadd_rn(ss, __fmul_rn(dj, dj)); }
    float sd = __fsqrt_rn(__fdiv_rn(ss, 11.f));
    float den = __fadd_rn(sd, 1e-8f);
#pragma unroll
    for (int j = 0; j < 12; j++) xs[sp * 12 + j][dl] = __fdiv_rn(__fsub_rn(v[j], m), den);
    if (d < ND) {
      MT[(size_t)(b * ND + d) * 64 + tc * 5 + sp] = __float2bfloat16(m);
      ST[(size_t)(b * ND + d) * 64 + tc * 5 + sp] = __float2bfloat16(sd);
    }
  }
  __syncthreads();
  // phase 3: norm^T chunk; tq-fast mapping -> 240B contiguous runs
  float* nt = dout + ((size_t)b * NOUT + 720) * ND;
  for (int i = tid; i < 64 * 15; i += 256) {
    int tq = i % 15, dl = i / 15, d = d0 + dl;
    if (d < ND) {
      float4 f;
      f.x = xs[tq * 4 + 0][dl]; f.y = xs[tq * 4 + 1][dl];
      f.z = xs[tq * 4 + 2][dl]; f.w = xs[tq * 4 + 3][dl];
      *(float4*)(nt + (size_t)d * 720 + t0 + tq * 4) = f;
    }
  }
}

__global__ __launch_bounds__(256) void k_mured(const double* __restrict__ muPart, float* __restrict__ mu) {
  int ser = blockIdx.x * 256 + threadIdx.x;
  if (ser < NSER) {
    const double* p = muPart + (size_t)ser * 12;
    double s = 0.0;
#pragma unroll
    for (int j = 0; j < 12; j++) s += p[j];
    mu[ser] = (float)(s / 720.0);
  }
}

// ---------------- fp64 FFT (720 = 16*9*5), 2 real series packed per block ----------------
// 128 threads/block (structural floor: ~43% occupancy, issue-bound).
#define PIDX(i) ((i) + ((i) >> 4))

__device__ __forceinline__ void dft3(double x0r, double x0i, double x1r, double x1i,
                                     double x2r, double x2i, double s3,
                                     double& y0r, double& y0i, double& y1r, double& y1i,
                                     double& y2r, double& y2i) {
  double ur = x1r + x2r, ui = x1i + x2i;
  double wr = x1r - x2r, wi = x1i - x2i;
  double mr = x0r - 0.5 * ur, mi = x0i - 0.5 * ui;
  y0r = x0r + ur;      y0i = x0i + ui;
  y1r = mr + s3 * wi;  y1i = mi - s3 * wr;
  y2r = mr - s3 * wi;  y2i = mi + s3 * wr;
}

__device__ __forceinline__ void dft4(double x0r, double x0i, double x1r, double x1i,
                                     double x2r, double x2i, double x3r, double x3i,
                                     double& y0r, double& y0i, double& y1r, double& y1i,
                                     double& y2r, double& y2i, double& y3r, double& y3i) {
  double a0r = x0r + x2r, a0i = x0i + x2i;
  double a1r = x0r - x2r, a1i = x0i - x2i;
  double a2r = x1r + x3r, a2i = x1i + x3i;
  double a3r = x1r - x3r, a3i = x1i - x3i;
  y0r = a0r + a2r; y0i = a0i + a2i;
  y2r = a0r - a2r; y2i = a0i - a2i;
  y1r = a1r + a3i; y1i = a1i - a3r;   // + (-i)*a3
  y3r = a1r - a3i; y3i = a1i + a3r;   // + (+i)*a3
}

__device__ __forceinline__ void cmulw(double& xr, double& xi, double2 w) {
  double r = xr * w.x - xi * w.y;
  double i = xr * w.y + xi * w.x;
  xr = r; xi = i;
}

__global__ __launch_bounds__(128) void k_fft(const float* __restrict__ dout, const double2* __restrict__ twg,
                                             unsigned short* __restrict__ selK, float* __restrict__ selA,
                                             float* __restrict__ selB, int* __restrict__ selCnt,
                                             int blkoff) {
  __shared__ double re[765], im[765];
  int ser0 = 2 * (blockIdx.x + blkoff);    // pairs never cross a batch (862 channels = even)
  int b = ser0 / ND, d0 = ser0 - b * ND;
  int tid = threadIdx.x;
  double s3 = -twg[240].y;                                 // sin(2*pi/3)
  double2 w9_1 = twg[80], w9_2 = twg[160], w9_4 = twg[320];
  double2 w16_1 = twg[45], w16_2 = twg[90], w16_3 = twg[135];
  double2 w16_4 = twg[180], w16_6 = twg[270], w16_9 = twg[405];
  double w5r[5], w5i[5];
#pragma unroll
  for (int j = 0; j < 5; j++) { double2 t = twg[144 * j]; w5r[j] = t.x; w5i[j] = t.y; }

  const float* row0 = dout + ((size_t)b * NOUT + 720) * ND + (size_t)d0 * 720;
  for (int n = tid; n < 720; n += 128) {
    re[PIDX(n)] = (double)row0[n];
    im[PIDX(n)] = (double)row0[720 + n];
  }
  __syncthreads();
  // step 1: 144 DFT-5 (stride 144)
  for (int task = tid; task < 144; task += 128) {
    double ar[5], ai[5], orr[5], oi[5];
#pragma unroll
    for (int n3 = 0; n3 < 5; n3++) { int p = PIDX(task + 144 * n3); ar[n3] = re[p]; ai[n3] = im[p]; }
    orr[0] = ar[0] + ar[1] + ar[2] + ar[3] + ar[4];
    oi[0]  = ai[0] + ai[1] + ai[2] + ai[3] + ai[4];
#pragma unroll
    for (int k3 = 1; k3 < 5; k3++) {
      double sr = ar[0], si = ai[0];
#pragma unroll
      for (int n3 = 1; n3 < 5; n3++) {
        int j = (n3 * k3) % 5;
        sr += ar[n3] * w5r[j] - ai[n3] * w5i[j];
        si += ar[n3] * w5i[j] + ai[n3] * w5r[j];
      }
      orr[k3] = sr; oi[k3] = si;
    }
#pragma unroll
    for (int k3 = 0; k3 < 5; k3++) { int p = PIDX(task + 144 * k3); re[p] = orr[k3]; im[p] = oi[k3]; }
  }
  __syncthreads();
  // step 2: 80 DFT-9 (stride 16) with pre-twiddle; 9 = 3x3 butterfly
  if (tid < 80) {
    int task = tid;
    int n1 = task & 15, k3 = task >> 4;
    double xr[9], xi[9];
#pragma unroll
    for (int n2 = 0; n2 < 9; n2++) {
      int p = PIDX(n1 + 16 * n2 + 144 * k3);
      double a = re[p], bb = im[p];
      double2 w = twg[16 * n2 * k3];        // < 720 always
      xr[n2] = a * w.x - bb * w.y;
      xi[n2] = a * w.y + bb * w.x;
    }
    double tr[3][3], ti[3][3];
#pragma unroll
    for (int a = 0; a < 3; a++)
      dft3(xr[a], xi[a], xr[a + 3], xi[a + 3], xr[a + 6], xi[a + 6], s3,
           tr[a][0], ti[a][0], tr[a][1], ti[a][1], tr[a][2], ti[a][2]);
    cmulw(tr[1][1], ti[1][1], w9_1);
    cmulw(tr[1][2], ti[1][2], w9_2);
    cmulw(tr[2][1], ti[2][1], w9_2);
    cmulw(tr[2][2], ti[2][2], w9_4);
#pragma unroll
    for (int c = 0; c < 3; c++) {
      double y0r, y0i, y1r, y1i, y2r, y2i;
      dft3(tr[0][c], ti[0][c], tr[1][c], ti[1][c], tr[2][c], ti[2][c], s3,
           y0r, y0i, y1r, y1i, y2r, y2i);
      int p0 = PIDX(n1 + 16 * (c + 0) + 144 * k3);
      int p1 = PIDX(n1 + 16 * (c + 3) + 144 * k3);
      int p2 = PIDX(n1 + 16 * (c + 6) + 144 * k3);
      re[p0] = y0r; im[p0] = y0i;
      re[p1] = y1r; im[p1] = y1i;
      re[p2] = y2r; im[p2] = y2i;
    }
  }
  __syncthreads();
  // step 3: 45 DFT-16 with pre-twiddle; 16 = 4x4 butterfly; write Z linear
  double vr[16], vi[16];
  int k2 = 0, k3 = 0;
  bool act = tid < 45;
  if (act) {
    k2 = tid % 9; k3 = tid / 9;
    int base = 16 * k2 + 144 * k3, tf = k3 + 5 * k2;
    int idx = 0;
#pragma unroll
    for (int n1 = 0; n1 < 16; n1++) {
      int p = PIDX(base + n1);
      double a = re[p], bb = im[p];
      double2 w = twg[idx];                 // idx = n1*tf <= 660
      vr[n1] = a * w.x - bb * w.y;
      vi[n1] = a * w.y + bb * w.x;
      idx += tf;
    }
  }
  __syncthreads();  // all reads done before overwriting with Z
  if (act) {
    int kbase = k3 + 5 * k2;
    double t1r[4][4], t1i[4][4];
#pragma unroll
    for (int a = 0; a < 4; a++)
      dft4(vr[a], vi[a], vr[a + 4], vi[a + 4], vr[a + 8], vi[a + 8], vr[a + 12], vi[a + 12],
           t1r[a][0], t1i[a][0], t1r[a][1], t1i[a][1],
           t1r[a][2], t1i[a][2], t1r[a][3], t1i[a][3]);
    cmulw(t1r[1][1], t1i[1][1], w16_1);
    cmulw(t1r[1][2], t1i[1][2], w16_2);
    cmulw(t1r[1][3], t1i[1][3], w16_3);
    cmulw(t1r[2][1], t1i[2][1], w16_2);
    cmulw(t1r[2][2], t1i[2][2], w16_4);
    cmulw(t1r[2][3], t1i[2][3], w16_6);
    cmulw(t1r[3][1], t1i[3][1], w16_3);
    cmulw(t1r[3][2], t1i[3][2], w16_6);
    cmulw(t1r[3][3], t1i[3][3], w16_9);
#pragma unroll
    for (int c = 0; c < 4; c++) {
      double y0r, y0i, y1r, y1i, y2r, y2i, y3r, y3i;
      dft4(t1r[0][c], t1i[0][c], t1r[1][c], t1i[1][c],
           t1r[2][c], t1i[2][c], t1r[3][c], t1i[3][c],
           y0r, y0i, y1r, y1i, y2r, y2i, y3r, y3i);
      re[kbase + 45 * (c + 0)]  = y0r; im[kbase + 45 * (c + 0)]  = y0i;
      re[kbase + 45 * (c + 4)]  = y1r; im[kbase + 45 * (c + 4)]  = y1i;
      re[kbase + 45 * (c + 8)]  = y2r; im[kbase + 45 * (c + 8)]  = y2i;
      re[kbase + 45 * (c + 12)] = y3r; im[kbase + 45 * (c + 12)] = y3i;
    }
  }
  __syncthreads();
  // wave 0 -> series A, wave 1 -> series B (concurrent selection).
  int lane = tid & 63, wv = tid >> 6;
  unsigned long long key[6];
#pragma unroll
  for (int j = 0; j < 6; j++) {
    int k = lane + 64 * j;
    if (k <= 360) {
      int mk = (k == 0) ? 0 : 720 - k;
      double zr = re[k], zi = im[k], wr = re[mk], wi = im[mk];
      double m2;
      if (wv == 0) {
        double ra = 0.5 * (zr + wr), ia = 0.5 * (zi - wi);
        m2 = ra * ra + ia * ia;
      } else {
        double rb = 0.5 * (zi + wi), ib = 0.5 * (wr - zr);
        m2 = rb * rb + ib * ib;
      }
      key[j] = (__double_as_longlong(m2) & ~0x1FFull) | (unsigned long long)(511 - k);
    } else {
      key[j] = 0ull;
    }
  }
#define CSWP(a, b) { unsigned long long ka = key[a], kb = key[b]; \
                     key[a] = ka > kb ? ka : kb; key[b] = ka > kb ? kb : ka; }
  CSWP(0,1) CSWP(1,2) CSWP(2,3) CSWP(3,4) CSWP(4,5)
  CSWP(0,1) CSWP(1,2) CSWP(2,3) CSWP(3,4)
  CSWP(0,1) CSWP(1,2) CSWP(2,3)
  CSWP(0,1) CSWP(1,2)
  CSWP(0,1)
#undef CSWP
  {
    int ser = ser0 + wv;
    bool isB = (wv == 1);
    int used = 0, cnt = 0;
    while (used < 30) {
      unsigned long long m = key[0];
#pragma unroll
      for (int off = 32; off; off >>= 1) {
        unsigned long long o = __shfl_xor(m, off);
        m = (o > m) ? o : m;
      }
      int bk = 511 - (int)(m & 0x1FF);
      int w = (bk == 0 || bk == 360) ? 1 : 2;
      int take = (30 - used < w) ? (30 - used) : w;
      bool own = (key[0] == m);     // keys globally unique -> exactly one owner
      if (own) {
        int mk = (bk == 0) ? 0 : 720 - bk;
        double zr = re[bk], zi = im[bk], wr = re[mk], wi = im[mk];
        double cr, ci;
        if (!isB) { cr = 0.5 * (zr + wr); ci = 0.5 * (zi - wi); }
        else      { cr = 0.5 * (zi + wi); ci = 0.5 * (wr - zr); }
        double scale = (double)take / 720.0;
        selK[(size_t)ser * 32 + cnt] = (unsigned short)bk;
        selA[(size_t)ser * 32 + cnt] = (float)(scale * cr);
        selB[(size_t)ser * 32 + cnt] = (float)(scale * ci);
      }
      key[0] = own ? key[1] : key[0];
      key[1] = own ? key[2] : key[1];
      key[2] = own ? key[3] : key[2];
      key[3] = own ? key[4] : key[3];
      key[4] = own ? key[5] : key[4];
      key[5] = own ? 0ull   : key[5];
      used += take; cnt++;
    }
    if (lane == 0) selCnt[ser] = cnt;
  }
}

// ---------------- reconstruction: x_f, residual, bf16 A_f ----------------
// grid (14, 5, 32): 64 channels x 144 t per block (2240 blocks -> ~6 blocks/CU
// reachable, occupancy-limited VALU kernel); 12-wide t-tiles, 3 iters/wave.
__global__ __launch_bounds__(256, 6) void k_recon(float* __restrict__ dout, const unsigned short* __restrict__ selK,
                                                  const float* __restrict__ selA, const float* __restrict__ selB,
                                                  const int* __restrict__ selCnt, const double2* __restrict__ twg,
                                                  bf16* __restrict__ Af) {
  __shared__ unsigned short kk[64][31];
  __shared__ float AAc[64][31], BBc[64][31];
  __shared__ int cc[64];
  __shared__ float2 tbl[720];
  int b = blockIdx.z, tch = blockIdx.y, d0 = blockIdx.x * 64, tid = threadIdx.x;
  for (int j = tid; j < 720; j += 256) { double2 w = twg[j]; tbl[j] = make_float2((float)w.x, (float)w.y); }
  for (int i = tid; i < 64 * 30; i += 256) {
    int dl = i / 30, j = i - dl * 30, d = d0 + dl;
    if (d < ND) {
      size_t o = (size_t)(b * ND + d) * 32 + j;
      kk[dl][j] = selK[o]; AAc[dl][j] = selA[o]; BBc[dl][j] = selB[o];
    }
  }
  if (tid < 64) cc[tid] = (d0 + tid < ND) ? selCnt[b * ND + d0 + tid] : 0;
  if (tch == 0) {  // zero-pad Af cols 720..735 once
    for (int i = tid; i < 64 * 16; i += 256) {
      int r = i >> 4, c = 720 + (i & 15), dd = d0 + r;
      if (dd < ND) Af[(size_t)(b * ND + dd) * NKP + c] = __float2bfloat16(0.f);
    }
  }
  __syncthreads();
  int dl = tid & 63, tb = tid >> 6;
  int d = d0 + dl;
  bool valid = d < ND;
  const float* nrow = dout + ((size_t)b * NOUT + 720) * ND + (size_t)(valid ? d : 0) * 720;
  bf16* afrow = Af + (size_t)(b * ND + (valid ? d : 0)) * NKP;
  int n = cc[dl];
#pragma unroll
  for (int m = 0; m < 3; m++) {
    int t0 = tch * 144 + tb * 12 + m * 48;
    float a[12];
#pragma unroll
    for (int r = 0; r < 12; r++) a[r] = 0.f;
    for (int j = 0; j < n; j++) {
      int k = kk[dl][j];
      float Aj = AAc[dl][j], Bj = BBc[dl][j];
      float2 w = tbl[k];                       // e^{-i*2pi*k/720}
      float2 c = tbl[(k * t0) % 720];          // e^{-i*2pi*k*t0/720}
#pragma unroll
      for (int r = 0; r < 12; r++) {
        a[r] = fmaf(Aj, c.x, fmaf(Bj, c.y, a[r]));
        if (r < 11) {
          float nx = c.x * w.x - c.y * w.y;
          float ny = c.x * w.y + c.y * w.x;
          c.x = nx; c.y = ny;
        }
      }
    }
    if (valid) {
      union { bf16 h[12]; short4v v[3]; } u;
#pragma unroll
      for (int r = 0; r < 12; r++) u.h[r] = __float2bfloat16(a[r]);
      *(short4v*)(afrow + t0 + 0) = u.v[0];
      *(short4v*)(afrow + t0 + 4) = u.v[1];
      *(short4v*)(afrow + t0 + 8) = u.v[2];
      float4 n0 = *(const float4*)(nrow + t0 + 0);
      float4 n1 = *(const float4*)(nrow + t0 + 4);
      float4 n2 = *(const float4*)(nrow + t0 + 8);
      const float nv[12] = {n0.x, n0.y, n0.z, n0.w, n1.x, n1.y, n1.z, n1.w,
                            n2.x, n2.y, n2.z, n2.w};
#pragma unroll
      for (int r = 0; r < 12; r++)
        dout[((size_t)b * NOUT + (t0 + r)) * ND + d] = nv[r] - a[r];
    }
  }
}

// ---------------- MFMA GEMM, C = A(Mrows x K) * W(N x K)^T ----------------
// 2-phase double-buffered K-loop; BM/WAVES template picks tiling.
template <int BM, int BN, int MODE, bool XCD, int WAVES>
__global__ __launch_bounds__(WAVES * 64) void k_gemm(const bf16* __restrict__ A, int lda,
                                              const bf16* __restrict__ W, int ldb, int Ktiles,
                                              const float* __restrict__ bias, const float* __restrict__ rowMu,
                                              const float* __restrict__ colS, bf16* __restrict__ Hout, int hldc,
                                              int hoff, float* __restrict__ dout, const float* __restrict__ wgt,
                                              const float* __restrict__ meanall, int Mtiles, int Mrows) {
  __shared__ bf16 sA[2 * BM * 32];
  __shared__ bf16 sB[2 * BN * 32];
  const int M = Mrows;
  int Ntiles = gridDim.x / Mtiles;
  int bid = blockIdx.x;
  int mt, nt;
  if constexpr (XCD) {  // same-A blocks 8 apart (same XCD), consecutive in dispatch
    int xg = bid & 7, q = bid >> 3;
    nt = q % Ntiles;
    mt = (q / Ntiles) * 8 + xg;
  } else {
    mt = bid % Mtiles; nt = bid / Mtiles;
  }
  int tid = threadIdx.x, wave = tid >> 6, lane = tid & 63;
  constexpr int RN = BN / 32;
  constexpr int MI = (2 * BM) / (16 * WAVES);
  static_assert(MI >= 1, "bad tiling");
  int wr = (wave >> 1) * (16 * MI);
  int wc = (wave & 1) * (BN / 2);
  f32x4 zero = {0.f, 0.f, 0.f, 0.f};
  f32x4 acc[MI][RN];
#pragma unroll
  for (int i = 0; i < MI; i++)
#pragma unroll
    for (int j = 0; j < RN; j++) acc[i][j] = zero;
  int rl = lane >> 2;             // row within 16-row group
  int cb = (lane & 3) * 8;        // k-element offset of this lane's 16B

  constexpr int ACH = BM / 16, BCH = BN / 16;
  auto stage = [&](int buf, int kt) {
    for (int c = wave; c < ACH + BCH; c += WAVES) {
      if (c < ACH) {
        int grow = mt * BM + c * 16 + rl;
        if (grow > M - 1) grow = M - 1;
        gload16(A + (size_t)grow * lda + kt * 32 + cb,
                (char*)sA + (size_t)buf * (BM * 64) + (size_t)(c * 16) * 64);
      } else {
        int i = c - ACH;
        int gn = nt * BN + i * 16 + rl;
        gload16(W + (size_t)gn * ldb + kt * 32 + cb,
                (char*)sB + (size_t)buf * (BN * 64) + (size_t)(i * 16) * 64);
      }
    }
  };

  stage(0, 0);
  __syncthreads();
  for (int kt = 0; kt < Ktiles; kt++) {
    int cur = kt & 1;
    if (kt + 1 < Ktiles) stage(cur ^ 1, kt + 1);   // prefetch next tile
    int r16 = lane & 15, kb = (lane >> 4) * 16;
    const char* baseA = (const char*)sA + (size_t)cur * (BM * 64);
    const char* baseB = (const char*)sB + (size_t)cur * (BN * 64);
    short8 av[MI], bv[RN];
#pragma unroll
    for (int mi = 0; mi < MI; mi++)
      av[mi] = *(const short8*)(baseA + (size_t)(wr + mi * 16 + r16) * 64 + kb);
#pragma unroll
    for (int ni = 0; ni < RN; ni++)
      bv[ni] = *(const short8*)(baseB + (size_t)(wc + ni * 16 + r16) * 64 + kb);
#pragma unroll
    for (int mi = 0; mi < MI; mi++)
#pragma unroll
      for (int ni = 0; ni < RN; ni++)
        acc[mi][ni] = __builtin_amdgcn_mfma_f32_16x16x32_bf16(av[mi], bv[ni], acc[mi][ni], 0, 0, 0);
    __syncthreads();   // drains prefetch + guards buffer reuse
  }
  int cr = (lane >> 4) * 4, ccol = lane & 15;
#pragma unroll
  for (int mi = 0; mi < MI; mi++) {
#pragma unroll
    for (int ni = 0; ni < RN; ni++) {
      int gm0 = mt * BM + wr + mi * 16 + cr;
      int gn = nt * BN + wc + ni * 16 + ccol;
      f32x4 c = acc[mi][ni];
      if constexpr (MODE == 0 || MODE == 1) {
        float bb = bias[gn];
        float cs = (MODE == 0) ? colS[gn] : 0.f;
#pragma unroll
        for (int r = 0; r < 4; r++) {
          int gm = gm0 + r;
          if (gm < M) {
            float v = c[r] + bb;
            if constexpr (MODE == 0) v = tanhf(v - rowMu[gm] * cs);
            else v = fmaxf(v, 0.f);
            Hout[(size_t)gm * hldc + hoff + gn] = __float2bfloat16(v);
          }
        }
      } else if constexpr (MODE == 2 || MODE == 3) {
        if (gn < 60) {
          float bb = bias[gn];
#pragma unroll
          for (int r = 0; r < 4; r++) {
            int gm = gm0 + r;
            if (gm < M) {
              int bI = gm / ND, dd = gm - bI * ND;
              float v;
              if constexpr (MODE == 2) v = (c[r] + bb) * wgt[dd] + meanall[gm] * wgt[ND + dd];
              else v = fmaxf(c[r] + bb, 0.f);
              constexpr int rowoff = (MODE == 2) ? 1440 : 1500;
              dout[((size_t)bI * NOUT + rowoff + gn) * ND + dd] = v;
            }
          }
        }
      } else {  // MODE 6: rows = f2 output index p, cols = series (coalesced)
        int bI = gn / ND, dd = gn - bI * ND;
#pragma unroll
        for (int r = 0; r < 4; r++) {
          int pp = gm0 + r;
          if (pp < 720) {
            dout[((size_t)bI * NOUT + 720 + pp) * ND + dd] = c[r] + bias[pp];
          }
        }
      }
    }
  }
}

// ---------------- launcher ----------------

extern "C" void kernel_launch(void* const* d_in, const int* in_sizes, int n_in,
                              void* d_out, int out_size, void* d_ws, size_t ws_size,
                              hipStream_t stream) {
  (void)in_sizes; (void)n_in; (void)out_size; (void)ws_size;
  const float* x       = (const float*)d_in[0];
  const float* w_in_m  = (const float*)d_in[1];
  const float* b_in_m  = (const float*)d_in[2];
  const float* w_raw_m = (const float*)d_in[3];
  const float* b_raw_m = (const float*)d_in[4];
  const float* w_out_m = (const float*)d_in[5];
  const float* b_out_m = (const float*)d_in[6];
  const float* w_in_s  = (const float*)d_in[7];
  const float* b_in_s  = (const float*)d_in[8];
  const float* w_raw_s = (const float*)d_in[9];
  const float* b_raw_s = (const float*)d_in[10];
  const float* w_out_s = (const float*)d_in[11];
  const float* b_out_s = (const float*)d_in[12];
  const float* w_f1    = (const float*)d_in[13];
  const float* b_f1    = (const float*)d_in[14];
  const float* w_f2    = (const float*)d_in[15];
  const float* b_f2    = (const float*)d_in[16];
  const float* wgt     = (const float*)d_in[17];
  float* out = (float*)d_out;

  char* p = (char*)d_ws;
  size_t off = 0;
  auto carve = [&](size_t bytes) { char* r = p + off; off += (bytes + 255) & ~(size_t)255; return r; };

  bf16* AT      = (bf16*)carve((size_t)NSER * NKP * 2);
  bf16* Af      = (bf16*)carve((size_t)NSER * NKP * 2);
  bf16* MT      = (bf16*)carve((size_t)NSER * 64 * 2);
  bf16* ST      = (bf16*)carve((size_t)NSER * 64 * 2);
  bf16* Hf      = (bf16*)carve((size_t)NSER * 64 * 2);
  float* mu     = (float*)carve((size_t)NSER * 4);
  double* muPart = (double*)carve((size_t)NSER * 12 * 8);
  double2* tw   = (double2*)carve(720 * sizeof(double2));
  bf16* Wb_in_m  = (bf16*)carve((size_t)512 * 64 * 2);
  bf16* Wb_raw_m = (bf16*)carve((size_t)512 * NKP * 2);
  bf16* Wb_in_s  = (bf16*)carve((size_t)512 * 64 * 2);
  bf16* Wb_raw_s = (bf16*)carve((size_t)512 * NKP * 2);
  bf16* Wb_out_m = (bf16*)carve((size_t)64 * 1024 * 2);
  bf16* Wb_out_s = (bf16*)carve((size_t)64 * 1024 * 2);
  bf16* Wb_f1    = (bf16*)carve((size_t)64 * NKP * 2);
  bf16* Wb_f2    = (bf16*)carve((size_t)768 * 64 * 2);
  float* S_in    = (float*)carve(512 * 4);
  float* S_raw   = (float*)carve(512 * 4);
  // sel arrays are dead before H is first written -> overlay H on them
  char* selBase = p + off;
  unsigned short* selK = (unsigned short*)carve((size_t)NSER * 32 * 2);
  float* selA   = (float*)carve((size_t)NSER * 32 * 4);
  float* selB   = (float*)carve((size_t)NSER * 32 * 4);
  int* selCnt   = (int*)carve((size_t)NSER * 4);
  bf16* H = (bf16*)selBase;  // 27584 x 1024 bf16 (56.5 MB), reuses sel region

  k_init<<<512, 256, 0, stream>>>(w_in_m, w_raw_m, w_in_s, w_raw_s, w_out_m, w_out_s, w_f1, w_f2,
                                  tw, Wb_in_m, Wb_raw_m, Wb_in_s, Wb_raw_s, Wb_out_m, Wb_out_s,
                                  Wb_f1, Wb_f2, S_in, S_raw);

  k_prep<<<14 * 12 * 32, 256, 0, stream>>>(x, out, AT, MT, ST, muPart);
  k_mured<<<(NSER + 255) / 256, 256, 0, stream>>>(muPart, mu);
  k_fft<<<NSER / 4, 128, 0, stream>>>(out, tw, selK, selA, selB, selCnt, 0);
  k_fft<<<NSER / 4, 128, 0, stream>>>(out, tw, selK, selA, selB, selCnt, NSER / 4);
  k_recon<<<dim3(14, 5, 32), 256, 0, stream>>>(out, selK, selA, selB, selCnt, tw, Af);

  // mean MLP
  k_gemm<128, 128, 0, true, 8><<<NMT * 4, 512, 0, stream>>>(MT, 64, Wb_in_m, 64, 2, b_in_m, mu, S_in, H, 1024, 0,
                                                            nullptr, nullptr, nullptr, NMT, NSER);
  k_gemm<128, 128, 0, true, 8><<<NMT * 4, 512, 0, stream>>>(AT, NKP, Wb_raw_m, NKP, 23, b_raw_m, mu, S_raw, H, 1024, 512,
                                                            nullptr, nullptr, nullptr, NMT, NSER);
  k_gemm<64, 64, 2, true, 8><<<NMT64, 512, 0, stream>>>(H, 1024, Wb_out_m, 1024, 32, b_out_m, nullptr, nullptr,
                                                        nullptr, 0, 0, out, wgt, mu, NMT64, NSER);
  // std MLP (reuses H)
  k_gemm<128, 128, 1, true, 8><<<NMT * 4, 512, 0, stream>>>(ST, 64, Wb_in_s, 64, 2, b_in_s, nullptr, nullptr, H, 1024, 0,
                                                            nullptr, nullptr, nullptr, NMT, NSER);
  k_gemm<128, 128, 1, true, 8><<<NMT * 4, 512, 0, stream>>>(AT, NKP, Wb_raw_s, NKP, 23, b_raw_s, nullptr, nullptr, H, 1024, 512,
                                                            nullptr, nullptr, nullptr, NMT, NSER);
  k_gemm<64, 64, 3, true, 8><<<NMT64, 512, 0, stream>>>(H, 1024, Wb_out_s, 1024, 32, b_out_s, nullptr, nullptr,
                                                        nullptr, 0, 0, out, nullptr, nullptr, NMT64, NSER);
  // main-frequency MLP
  k_gemm<64, 64, 1, true, 8><<<NMT64, 512, 0, stream>>>(Af, NKP, Wb_f1, NKP, 23, b_f1, nullptr, nullptr, Hf, 64, 0,
                                                        nullptr, nullptr, nullptr, NMT64, NSER);
  // pred_main: transposed GEMM, coalesced stores over the series dim
  k_gemm<128, 64, 6, false, 4><<<6 * (NSER / 64), 256, 0, stream>>>(Wb_f2, 64, Hf, 64, 2, b_f2, nullptr, nullptr,
                                                                    nullptr, 0, 0, out, nullptr, nullptr, 6, 768);
}